// Round 1
// baseline (4551.378 us; speedup 1.0000x reference)
//
#include <hip/hip_runtime.h>
#include <math.h>

#define BB 4
#define NN 1024
#define KK 512
#define HH 8
#define DHh 64
#define HIDd 2048
#define BN (BB*NN)

// ---------------------------------------------------------------- helpers
__device__ __forceinline__ float gelu_tanh(float x){
    float x3 = x*x*x;
    float t = tanhf(0.7978845608028654f*(x + 0.044715f*x3));
    return 0.5f*x*(1.0f+t);
}

// ---------------------------------------------------------------- GEMM
// C = A(M,Kc) @ B(Kc,Nc) [+bias][+gelu], batched via grid.z with strides.
__global__ __launch_bounds__(256) void gemm_k(
    const float* __restrict__ A, const float* __restrict__ Bm, float* __restrict__ C,
    int M, int Kc, int Nc, long sA, long sB, long sC,
    const float* __restrict__ bias, int act)
{
    __shared__ float As[16][64];   // [k][m]
    __shared__ float Bs[16][64];   // [k][n]
    const int bz = blockIdx.z;
    const float* Ab = A + (long)bz*sA;
    const float* Bb = Bm + (long)bz*sB;
    float* Cb = C + (long)bz*sC;
    const int tid = threadIdx.x;
    const int tx = tid & 15, ty = tid >> 4;
    const int n0 = blockIdx.x * 64;
    const int m0 = blockIdx.y * 64;
    const int a_m = tid >> 2, a_k4 = (tid & 3) * 4;
    const int b_k = tid >> 4, b_n4 = (tid & 15) * 4;
    float acc[4][4] = {};
    for (int k0 = 0; k0 < Kc; k0 += 16){
        float4 av = *(const float4*)(Ab + (long)(m0 + a_m)*Kc + k0 + a_k4);
        float4 bv = *(const float4*)(Bb + (long)(k0 + b_k)*Nc + n0 + b_n4);
        As[a_k4+0][a_m] = av.x; As[a_k4+1][a_m] = av.y;
        As[a_k4+2][a_m] = av.z; As[a_k4+3][a_m] = av.w;
        *(float4*)&Bs[b_k][b_n4] = bv;
        __syncthreads();
        #pragma unroll
        for (int kk = 0; kk < 16; ++kk){
            float4 a4 = *(const float4*)&As[kk][ty<<2];
            float4 b4 = *(const float4*)&Bs[kk][tx<<2];
            float a_[4] = {a4.x,a4.y,a4.z,a4.w};
            float b_[4] = {b4.x,b4.y,b4.z,b4.w};
            #pragma unroll
            for (int i=0;i<4;i++)
                #pragma unroll
                for (int j=0;j<4;j++)
                    acc[i][j] = fmaf(a_[i], b_[j], acc[i][j]);
        }
        __syncthreads();
    }
    #pragma unroll
    for (int i=0;i<4;i++){
        long m = m0 + (ty<<2) + i;
        int n = n0 + (tx<<2);
        float o_[4];
        #pragma unroll
        for (int j=0;j<4;j++){
            float v = acc[i][j];
            if (bias) v += bias[n+j];
            if (act)  v = gelu_tanh(v);
            o_[j] = v;
        }
        float4 o4 = make_float4(o_[0],o_[1],o_[2],o_[3]);
        *(float4*)(Cb + m*Nc + n) = o4;
    }
}

// ---------------------------------------------------------------- LayerNorm (rows of 512)
__global__ __launch_bounds__(256) void ln_k(
    const float* __restrict__ x, const float* __restrict__ g,
    const float* __restrict__ be, float* __restrict__ y)
{
    __shared__ float sh[8];
    const int r = blockIdx.x, tid = threadIdx.x;
    const float* xr = x + (long)r*KK;
    float2 v = *(const float2*)(xr + tid*2);
    float s = v.x+v.y, s2 = v.x*v.x+v.y*v.y;
    #pragma unroll
    for (int o=32;o>0;o>>=1){ s += __shfl_down(s,o); s2 += __shfl_down(s2,o); }
    if ((tid&63)==0){ sh[tid>>6]=s; sh[4+(tid>>6)]=s2; }
    __syncthreads();
    s  = sh[0]+sh[1]+sh[2]+sh[3];
    s2 = sh[4]+sh[5]+sh[6]+sh[7];
    const float mean = s*(1.f/KK);
    const float var  = s2*(1.f/KK) - mean*mean;
    const float rs = rsqrtf(var + 1e-5f);
    float2 gg = *(const float2*)(g + tid*2);
    float2 bb = *(const float2*)(be + tid*2);
    float2 o;
    o.x = (v.x-mean)*rs*gg.x + bb.x;
    o.y = (v.y-mean)*rs*gg.y + bb.y;
    *(float2*)(y + (long)r*KK + tid*2) = o;
}

// ---------------------------------------------------------------- small prep kernels
__global__ void square_k(const float* __restrict__ a, float* __restrict__ o, int n){
    int i = blockIdx.x*256 + threadIdx.x;
    if (i < n){ float v = a[i]; o[i] = v*v; }
}
__global__ void build_gt_k(const float* __restrict__ G, float* __restrict__ GT){
    int idx = blockIdx.x*256 + threadIdx.x;           // over 512*1536
    if (idx >= KK*3*KK) return;
    int l = idx / (3*KK); int c = idx % (3*KK);
    int g = c / KK; int k = c % KK;
    GT[idx] = G[((long)g*KK + k)*KK + l];
}
__global__ void combine_k(const float* __restrict__ t, const float* __restrict__ phi,
                          float* __restrict__ a, float sign){
    int idx = blockIdx.x*256 + threadIdx.x;           // float4 groups over BN*KK/4
    if (idx >= BN*KK/4) return;
    int r = idx >> 7;            // / (KK/4)
    int c4 = (idx & 127) << 2;
    const float* ph = phi + r*3;
    float p0 = sign*ph[0], p1 = sign*ph[1], p2 = sign*ph[2];
    const float* tr = t + (long)r*(3*KK);
    float4 t0 = *(const float4*)(tr + c4);
    float4 t1 = *(const float4*)(tr + KK + c4);
    float4 t2 = *(const float4*)(tr + 2*KK + c4);
    float4 o;
    o.x = p0*t0.x + p1*t1.x + p2*t2.x;
    o.y = p0*t0.y + p1*t1.y + p2*t2.y;
    o.z = p0*t0.z + p1*t1.z + p2*t2.z;
    o.w = p0*t0.w + p1*t1.w + p2*t2.w;
    *(float4*)(a + (long)r*KK + c4) = o;
}
// out = (res?res:0) + x + a1 + 0.5*a2
__global__ void tfinal_k(const float* __restrict__ x, const float* __restrict__ a1,
                         const float* __restrict__ a2, const float* __restrict__ res,
                         float* __restrict__ out){
    int i = blockIdx.x*256 + threadIdx.x;
    if (i >= BN*KK/4) return;
    float4 xv = ((const float4*)x)[i];
    float4 v1 = ((const float4*)a1)[i];
    float4 v2 = ((const float4*)a2)[i];
    float4 o;
    o.x = xv.x + v1.x + 0.5f*v2.x;
    o.y = xv.y + v1.y + 0.5f*v2.y;
    o.z = xv.z + v1.z + 0.5f*v2.z;
    o.w = xv.w + v1.w + 0.5f*v2.w;
    if (res){ float4 rv = ((const float4*)res)[i]; o.x+=rv.x; o.y+=rv.y; o.z+=rv.z; o.w+=rv.w; }
    ((float4*)out)[i] = o;
}
__global__ void copy_k(const float* __restrict__ s, float* __restrict__ d, int n4){
    int i = blockIdx.x*256 + threadIdx.x;
    if (i < n4) ((float4*)d)[i] = ((const float4*)s)[i];
}
__global__ void final_k(const float* __restrict__ a, const float* __restrict__ b,
                        const float* __restrict__ c, float* __restrict__ out){
    int i = blockIdx.x*256 + threadIdx.x;
    if (i >= BN*KK/4) return;
    float4 av = ((const float4*)a)[i], bv = ((const float4*)b)[i], cv = ((const float4*)c)[i];
    float4 o;
    o.x = av.x + bv.x - cv.x; o.y = av.y + bv.y - cv.y;
    o.z = av.z + bv.z - cv.z; o.w = av.w + bv.w - cv.w;
    ((float4*)out)[i] = o;
}
__global__ void ffn_update_k(float* __restrict__ h, const float* __restrict__ drive,
                             const float* __restrict__ bmh, const float* __restrict__ mup,
                             const float* __restrict__ lr){
    int i = blockIdx.x*256 + threadIdx.x;
    if (i >= BN*KK/4) return;
    const float lrv = *lr;
    float4 hv = ((float4*)h)[i];
    float4 dv = ((const float4*)drive)[i];
    float4 bv = ((const float4*)bmh)[i];
    float4 pv = ((const float4*)mup)[i];
    float4 o;
    o.x = hv.x + lrv*(dv.x - (1e-3f*(hv.x-pv.x) + 1.0f*(hv.x-bv.x)));
    o.y = hv.y + lrv*(dv.y - (1e-3f*(hv.y-pv.y) + 1.0f*(hv.y-bv.y)));
    o.z = hv.z + lrv*(dv.z - (1e-3f*(hv.z-pv.z) + 1.0f*(hv.z-bv.z)));
    o.w = hv.w + lrv*(dv.w - (1e-3f*(hv.w-pv.w) + 1.0f*(hv.w-bv.w)));
    ((float4*)h)[i] = o;
}

// ---------------------------------------------------------------- attention prep
// per (b,n,h) wave: inv=1/sq (in place over sq), qinv=q*inv, skk=sk+k^2 (in place),
// c = sum(q^2*inv + log sq), d = sum(log sk)
__global__ __launch_bounds__(64) void prep_k(
    const float* __restrict__ qm, const float* __restrict__ km,
    float* __restrict__ sqm, float* __restrict__ skm,
    float* __restrict__ qinvm, float* __restrict__ cvec, float* __restrict__ dvec)
{
    const int blk = blockIdx.x;     // (b*NN+n)*HH + h
    const int bn = blk >> 3, h = blk & 7;
    const int d = threadIdx.x;
    const long idx = (long)bn*KK + h*DHh + d;
    float sq = sqm[idx] + 1e-8f;
    float inv = 1.f/sq;
    float qv = qm[idx];
    float qi = qv*inv;
    sqm[idx] = inv;
    qinvm[idx] = qi;
    float sk = skm[idx] + 1e-8f;
    float kv = km[idx];
    skm[idx] = sk + kv*kv;
    float cv = qv*qi + __logf(sq);
    float dv = __logf(sk);
    #pragma unroll
    for (int o=32;o>0;o>>=1){ cv += __shfl_down(cv,o); dv += __shfl_down(dv,o); }
    if (d==0){
        int b = bn / NN, n = bn % NN;
        int o = (b*HH + h)*NN + n;
        cvec[o] = cv; dvec[o] = dv;
    }
}

// ---------------------------------------------------------------- fused KL attention
// one block per (b, row i): for each head -> scores, causal softmax, out=beta@V,
// accumulate beta_m (mean over heads) in LDS; write beta_m row at the end.
__global__ __launch_bounds__(256) void attn_k(
    const float* __restrict__ invm, const float* __restrict__ qinvm,
    const float* __restrict__ skkm, const float* __restrict__ km,
    const float* __restrict__ vm, const float* __restrict__ cvec,
    const float* __restrict__ dvec, float* __restrict__ outp,
    float* __restrict__ betam)
{
    __shared__ float s_beta[NN];
    __shared__ float s_bm[NN];
    __shared__ float s_inv[DHh];
    __shared__ float s_qinv[DHh];
    __shared__ float s_red[4];
    __shared__ float s_out[256];
    const int tid = threadIdx.x;
    const int b = blockIdx.x / NN;
    const int i = blockIdx.x % NN;
    for (int j=tid;j<NN;j+=256) s_bm[j]=0.f;
    const int L = i+1;
    for (int h=0; h<HH; ++h){
        __syncthreads();
        if (tid < DHh){
            long ib = (long)(b*NN+i)*KK + h*DHh + tid;
            s_inv[tid]  = invm[ib];
            s_qinv[tid] = qinvm[ib];
        }
        __syncthreads();
        const float ci = cvec[(b*HH+h)*NN + i];
        const float* dptr = dvec + (b*HH+h)*NN;
        float lmax = -3.0e38f;
        for (int j=tid;j<L;j+=256){
            const float4* skr = (const float4*)(skkm + (long)(b*NN+j)*KK + h*DHh);
            const float4* kr  = (const float4*)(km   + (long)(b*NN+j)*KK + h*DHh);
            float acc = 0.f;
            #pragma unroll
            for (int d4=0; d4<16; ++d4){
                float4 sv = skr[d4];
                float4 kv = kr[d4];
                float4 iv = *(const float4*)&s_inv[d4*4];
                float4 qv = *(const float4*)&s_qinv[d4*4];
                acc += iv.x*sv.x + iv.y*sv.y + iv.z*sv.z + iv.w*sv.w;
                acc -= 2.f*(qv.x*kv.x + qv.y*kv.y + qv.z*kv.z + qv.w*kv.w);
            }
            float sc = -0.5f*(acc + ci - dptr[j] - (float)DHh);
            s_beta[j] = sc;
            lmax = fmaxf(lmax, sc);
        }
        #pragma unroll
        for (int o=32;o>0;o>>=1) lmax = fmaxf(lmax, __shfl_down(lmax,o));
        if ((tid&63)==0) s_red[tid>>6] = lmax;
        __syncthreads();
        const float mx = fmaxf(fmaxf(s_red[0],s_red[1]), fmaxf(s_red[2],s_red[3]));
        float psum = 0.f;
        for (int j=tid;j<L;j+=256){
            float e = __expf(s_beta[j]-mx);
            s_beta[j] = e;
            psum += e;
        }
        #pragma unroll
        for (int o=32;o>0;o>>=1) psum += __shfl_down(psum,o);
        __syncthreads();
        if ((tid&63)==0) s_red[tid>>6] = psum;
        __syncthreads();
        const float isum = 1.f/(s_red[0]+s_red[1]+s_red[2]+s_red[3]);
        for (int j=tid;j<L;j+=256){
            float bb = s_beta[j]*isum;
            s_beta[j] = bb;
            s_bm[j] += 0.125f*bb;
        }
        __syncthreads();
        const int d = tid & 63, grp = tid >> 6;
        float part = 0.f;
        for (int j=grp;j<L;j+=4)
            part += s_beta[j]*vm[(long)(b*NN+j)*KK + h*DHh + d];
        s_out[tid] = part;
        __syncthreads();
        if (tid < 64){
            float o = s_out[tid] + s_out[tid+64] + s_out[tid+128] + s_out[tid+192];
            outp[(long)(b*NN+i)*KK + h*DHh + tid] = o;
        }
    }
    __syncthreads();
    for (int j=tid;j<NN;j+=256)
        betam[((long)b*NN+i)*NN + j] = (j<=i) ? s_bm[j] : 0.f;
}

// ---------------------------------------------------------------- launch
extern "C" void kernel_launch(void* const* d_in, const int* in_sizes, int n_in,
                              void* d_out, int out_size, void* d_ws, size_t ws_size,
                              hipStream_t stream) {
    const float* mu_q    = (const float*)d_in[0];
    const float* sigma_q = (const float*)d_in[1];
    const float* phi     = (const float*)d_in[2];
    const float* gen     = (const float*)d_in[3];
    // d_in[4] = causal mask (reconstructed analytically)
    const float* mu_prior= (const float*)d_in[5];
    const float* Wq = (const float*)d_in[6];
    const float* Wk = (const float*)d_in[7];
    const float* Wv = (const float*)d_in[8];
    const float* Wo = (const float*)d_in[9];
    const float* g1 = (const float*)d_in[10];
    const float* be1= (const float*)d_in[11];
    const float* g2 = (const float*)d_in[12];
    const float* be2= (const float*)d_in[13];
    const float* W1 = (const float*)d_in[14];
    const float* bh1= (const float*)d_in[15];
    const float* W2 = (const float*)d_in[16];
    const float* bh2= (const float*)d_in[17];
    const float* lr = (const float*)d_in[18];
    float* out = (float*)d_out;

    float* w = (float*)d_ws;
    size_t off = 0;
    auto alloc = [&](size_t n){ float* p = w + off; off += n; return p; };
    float* GTb  = alloc((size_t)KK*3*KK);      // 786432
    float* Wq2b = alloc((size_t)KK*KK);
    float* Wk2b = alloc((size_t)KK*KK);
    float* Xb   = alloc((size_t)BN*KK);        // mu_n -> mu_g -> attn_out
    float* Tb   = alloc((size_t)BN*3*KK);      // transport temp
    float* A1b  = alloc((size_t)BN*KK);        // a1 -> wo_out -> bmh
    float* A2b  = alloc((size_t)BN*KK);        // a2 -> a1'
    float* Qb   = alloc((size_t)BN*KK);        // q  -> a2'
    float* Kb   = alloc((size_t)BN*KK);        // k  -> mu_res
    float* Vb   = alloc((size_t)BN*KK);        // v  -> mu_n2
    float* SQb  = alloc((size_t)BN*KK);        // sq -> inv -> h
    float* SKb  = alloc((size_t)BN*KK);        // sk -> skk -> drive
    float* QIb  = alloc((size_t)BN*KK);        // qinv
    float* Cb_  = alloc((size_t)BB*HH*NN);
    float* Db_  = alloc((size_t)BB*HH*NN);
    float* BMb  = alloc((size_t)BB*NN*NN);     // beta_m
    float* Zb   = alloc((size_t)BN*HIDd);      // gelu hidden

    auto gemm = [&](const float* A, const float* Bm, float* C, int M, int Kc, int Nc,
                    const float* bias, int act){
        dim3 g(Nc/64, M/64, 1);
        gemm_k<<<g, 256, 0, stream>>>(A, Bm, C, M, Kc, Nc, 0L, 0L, 0L, bias, act);
    };

    // phase 0: weights prep
    square_k<<<(KK*KK+255)/256, 256, 0, stream>>>(Wq, Wq2b, KK*KK);
    square_k<<<(KK*KK+255)/256, 256, 0, stream>>>(Wk, Wk2b, KK*KK);
    build_gt_k<<<(KK*3*KK+255)/256, 256, 0, stream>>>(gen, GTb);

    // phase A: LN1 + forward transport
    ln_k<<<BN, 256, 0, stream>>>(mu_q, g1, be1, Xb);
    gemm(Xb, GTb, Tb, BN, KK, 3*KK, nullptr, 0);
    combine_k<<<BN*KK/4/256, 256, 0, stream>>>(Tb, phi, A1b, 1.f);
    gemm(A1b, GTb, Tb, BN, KK, 3*KK, nullptr, 0);
    combine_k<<<BN*KK/4/256, 256, 0, stream>>>(Tb, phi, A2b, 1.f);
    tfinal_k<<<BN*KK/4/256, 256, 0, stream>>>(Xb, A1b, A2b, nullptr, Xb);   // mu_g

    // phase B: projections + attention prep
    gemm(Xb, Wq, Qb, BN, KK, KK, nullptr, 0);
    gemm(Xb, Wk, Kb, BN, KK, KK, nullptr, 0);
    gemm(Xb, Wv, Vb, BN, KK, KK, nullptr, 0);
    gemm(sigma_q, Wq2b, SQb, BN, KK, KK, nullptr, 0);
    gemm(sigma_q, Wk2b, SKb, BN, KK, KK, nullptr, 0);
    prep_k<<<BN*HH, 64, 0, stream>>>(Qb, Kb, SQb, SKb, QIb, Cb_, Db_);

    // phase C: fused attention (writes attn_out into Xb, beta_m into BMb)
    attn_k<<<BN, 256, 0, stream>>>(SQb, QIb, SKb, Kb, Vb, Cb_, Db_, Xb, BMb);

    // phase D: output proj + back transport + residual + LN2
    gemm(Xb, Wo, A1b, BN, KK, KK, nullptr, 0);                               // wo_out
    gemm(A1b, GTb, Tb, BN, KK, 3*KK, nullptr, 0);
    combine_k<<<BN*KK/4/256, 256, 0, stream>>>(Tb, phi, A2b, -1.f);          // a1'
    gemm(A2b, GTb, Tb, BN, KK, 3*KK, nullptr, 0);
    combine_k<<<BN*KK/4/256, 256, 0, stream>>>(Tb, phi, Qb, -1.f);           // a2'
    tfinal_k<<<BN*KK/4/256, 256, 0, stream>>>(A1b, A2b, Qb, mu_q, Kb);       // mu_res
    ln_k<<<BN, 256, 0, stream>>>(Kb, g2, be2, Vb);                           // mu_n2
    copy_k<<<BN*KK/4/256, 256, 0, stream>>>(Vb, SQb, BN*KK/4);               // h = mu_n2

    // phase E: 2 VFE iterations
    for (int it=0; it<2; ++it){
        gemm(SQb, W1, Zb, BN, KK, HIDd, bh1, 1);                             // gelu(h@W1+b1)
        gemm(Zb, W2, SKb, BN, HIDd, KK, bh2, 0);                             // drive
        {   // bmh = beta_m @ h   (batched over B)
            dim3 g(KK/64, NN/64, BB);
            gemm_k<<<g, 256, 0, stream>>>(BMb, SQb, A1b, NN, NN, KK,
                                          (long)NN*NN, (long)NN*KK, (long)NN*KK,
                                          nullptr, 0);
        }
        ffn_update_k<<<BN*KK/4/256, 256, 0, stream>>>(SQb, SKb, A1b, mu_prior, lr);
    }

    // phase F: outputs
    final_k<<<BN*KK/4/256, 256, 0, stream>>>(Kb, SQb, Vb, out);              // mu_out
    copy_k<<<BN*KK/4/256, 256, 0, stream>>>(sigma_q, out + (size_t)BN*KK, BN*KK/4);
    copy_k<<<(BN*3/4+255)/256, 256, 0, stream>>>(phi, out + 2*(size_t)BN*KK, BN*3/4);

    (void)in_sizes; (void)n_in; (void)out_size; (void)ws_size;
}

// Round 2
// 2191.389 us; speedup vs baseline: 2.0769x; 2.0769x over previous
//
#include <hip/hip_runtime.h>
#include <math.h>

#define BB 4
#define NN 1024
#define KK 512
#define HH 8
#define DHh 64
#define HIDd 2048
#define BN (BB*NN)

// ---------------------------------------------------------------- helpers
__device__ __forceinline__ float gelu_tanh(float x){
    float x3 = x*x*x;
    float t = tanhf(0.7978845608028654f*(x + 0.044715f*x3));
    return 0.5f*x*(1.0f+t);
}

// ---------------------------------------------------------------- GEMM
// C = A(M,Kc) @ B(Kc,Nc) [+bias][+gelu], batched via grid.z with strides.
__global__ __launch_bounds__(256) void gemm_k(
    const float* __restrict__ A, const float* __restrict__ Bm, float* __restrict__ C,
    int M, int Kc, int Nc, long sA, long sB, long sC,
    const float* __restrict__ bias, int act)
{
    __shared__ float As[16][64];   // [k][m]
    __shared__ float Bs[16][64];   // [k][n]
    const int bz = blockIdx.z;
    const float* Ab = A + (long)bz*sA;
    const float* Bb = Bm + (long)bz*sB;
    float* Cb = C + (long)bz*sC;
    const int tid = threadIdx.x;
    const int tx = tid & 15, ty = tid >> 4;
    const int n0 = blockIdx.x * 64;
    const int m0 = blockIdx.y * 64;
    const int a_m = tid >> 2, a_k4 = (tid & 3) * 4;
    const int b_k = tid >> 4, b_n4 = (tid & 15) * 4;
    float acc[4][4] = {};
    for (int k0 = 0; k0 < Kc; k0 += 16){
        float4 av = *(const float4*)(Ab + (long)(m0 + a_m)*Kc + k0 + a_k4);
        float4 bv = *(const float4*)(Bb + (long)(k0 + b_k)*Nc + n0 + b_n4);
        As[a_k4+0][a_m] = av.x; As[a_k4+1][a_m] = av.y;
        As[a_k4+2][a_m] = av.z; As[a_k4+3][a_m] = av.w;
        *(float4*)&Bs[b_k][b_n4] = bv;
        __syncthreads();
        #pragma unroll
        for (int kk = 0; kk < 16; ++kk){
            float4 a4 = *(const float4*)&As[kk][ty<<2];
            float4 b4 = *(const float4*)&Bs[kk][tx<<2];
            float a_[4] = {a4.x,a4.y,a4.z,a4.w};
            float b_[4] = {b4.x,b4.y,b4.z,b4.w};
            #pragma unroll
            for (int i=0;i<4;i++)
                #pragma unroll
                for (int j=0;j<4;j++)
                    acc[i][j] = fmaf(a_[i], b_[j], acc[i][j]);
        }
        __syncthreads();
    }
    #pragma unroll
    for (int i=0;i<4;i++){
        long m = m0 + (ty<<2) + i;
        int n = n0 + (tx<<2);
        float o_[4];
        #pragma unroll
        for (int j=0;j<4;j++){
            float v = acc[i][j];
            if (bias) v += bias[n+j];
            if (act)  v = gelu_tanh(v);
            o_[j] = v;
        }
        float4 o4 = make_float4(o_[0],o_[1],o_[2],o_[3]);
        *(float4*)(Cb + m*Nc + n) = o4;
    }
}

// ---------------------------------------------------------------- LayerNorm (rows of 512)
__global__ __launch_bounds__(256) void ln_k(
    const float* __restrict__ x, const float* __restrict__ g,
    const float* __restrict__ be, float* __restrict__ y)
{
    __shared__ float sh[8];
    const int r = blockIdx.x, tid = threadIdx.x;
    const float* xr = x + (long)r*KK;
    float2 v = *(const float2*)(xr + tid*2);
    float s = v.x+v.y, s2 = v.x*v.x+v.y*v.y;
    #pragma unroll
    for (int o=32;o>0;o>>=1){ s += __shfl_down(s,o); s2 += __shfl_down(s2,o); }
    if ((tid&63)==0){ sh[tid>>6]=s; sh[4+(tid>>6)]=s2; }
    __syncthreads();
    s  = sh[0]+sh[1]+sh[2]+sh[3];
    s2 = sh[4]+sh[5]+sh[6]+sh[7];
    const float mean = s*(1.f/KK);
    const float var  = s2*(1.f/KK) - mean*mean;
    const float rs = rsqrtf(var + 1e-5f);
    float2 gg = *(const float2*)(g + tid*2);
    float2 bb = *(const float2*)(be + tid*2);
    float2 o;
    o.x = (v.x-mean)*rs*gg.x + bb.x;
    o.y = (v.y-mean)*rs*gg.y + bb.y;
    *(float2*)(y + (long)r*KK + tid*2) = o;
}

// ---------------------------------------------------------------- small prep kernels
__global__ void square_k(const float* __restrict__ a, float* __restrict__ o, int n){
    int i = blockIdx.x*256 + threadIdx.x;
    if (i < n){ float v = a[i]; o[i] = v*v; }
}
__global__ void build_gt_k(const float* __restrict__ G, float* __restrict__ GT){
    int idx = blockIdx.x*256 + threadIdx.x;           // over 512*1536
    if (idx >= KK*3*KK) return;
    int l = idx / (3*KK); int c = idx % (3*KK);
    int g = c / KK; int k = c % KK;
    GT[idx] = G[((long)g*KK + k)*KK + l];
}
__global__ void combine_k(const float* __restrict__ t, const float* __restrict__ phi,
                          float* __restrict__ a, float sign){
    int idx = blockIdx.x*256 + threadIdx.x;           // float4 groups over BN*KK/4
    if (idx >= BN*KK/4) return;
    int r = idx >> 7;            // / (KK/4)
    int c4 = (idx & 127) << 2;
    const float* ph = phi + r*3;
    float p0 = sign*ph[0], p1 = sign*ph[1], p2 = sign*ph[2];
    const float* tr = t + (long)r*(3*KK);
    float4 t0 = *(const float4*)(tr + c4);
    float4 t1 = *(const float4*)(tr + KK + c4);
    float4 t2 = *(const float4*)(tr + 2*KK + c4);
    float4 o;
    o.x = p0*t0.x + p1*t1.x + p2*t2.x;
    o.y = p0*t0.y + p1*t1.y + p2*t2.y;
    o.z = p0*t0.z + p1*t1.z + p2*t2.z;
    o.w = p0*t0.w + p1*t1.w + p2*t2.w;
    *(float4*)(a + (long)r*KK + c4) = o;
}
// out = (res?res:0) + x + a1 + 0.5*a2
__global__ void tfinal_k(const float* __restrict__ x, const float* __restrict__ a1,
                         const float* __restrict__ a2, const float* __restrict__ res,
                         float* __restrict__ out){
    int i = blockIdx.x*256 + threadIdx.x;
    if (i >= BN*KK/4) return;
    float4 xv = ((const float4*)x)[i];
    float4 v1 = ((const float4*)a1)[i];
    float4 v2 = ((const float4*)a2)[i];
    float4 o;
    o.x = xv.x + v1.x + 0.5f*v2.x;
    o.y = xv.y + v1.y + 0.5f*v2.y;
    o.z = xv.z + v1.z + 0.5f*v2.z;
    o.w = xv.w + v1.w + 0.5f*v2.w;
    if (res){ float4 rv = ((const float4*)res)[i]; o.x+=rv.x; o.y+=rv.y; o.z+=rv.z; o.w+=rv.w; }
    ((float4*)out)[i] = o;
}
__global__ void copy_k(const float* __restrict__ s, float* __restrict__ d, int n4){
    int i = blockIdx.x*256 + threadIdx.x;
    if (i < n4) ((float4*)d)[i] = ((const float4*)s)[i];
}
__global__ void final_k(const float* __restrict__ a, const float* __restrict__ b,
                        const float* __restrict__ c, float* __restrict__ out){
    int i = blockIdx.x*256 + threadIdx.x;
    if (i >= BN*KK/4) return;
    float4 av = ((const float4*)a)[i], bv = ((const float4*)b)[i], cv = ((const float4*)c)[i];
    float4 o;
    o.x = av.x + bv.x - cv.x; o.y = av.y + bv.y - cv.y;
    o.z = av.z + bv.z - cv.z; o.w = av.w + bv.w - cv.w;
    ((float4*)out)[i] = o;
}
__global__ void ffn_update_k(float* __restrict__ h, const float* __restrict__ drive,
                             const float* __restrict__ bmh, const float* __restrict__ mup,
                             const float* __restrict__ lr){
    int i = blockIdx.x*256 + threadIdx.x;
    if (i >= BN*KK/4) return;
    const float lrv = *lr;
    float4 hv = ((float4*)h)[i];
    float4 dv = ((const float4*)drive)[i];
    float4 bv = ((const float4*)bmh)[i];
    float4 pv = ((const float4*)mup)[i];
    float4 o;
    o.x = hv.x + lrv*(dv.x - (1e-3f*(hv.x-pv.x) + 1.0f*(hv.x-bv.x)));
    o.y = hv.y + lrv*(dv.y - (1e-3f*(hv.y-pv.y) + 1.0f*(hv.y-bv.y)));
    o.z = hv.z + lrv*(dv.z - (1e-3f*(hv.z-pv.z) + 1.0f*(hv.z-bv.z)));
    o.w = hv.w + lrv*(dv.w - (1e-3f*(hv.w-pv.w) + 1.0f*(hv.w-bv.w)));
    ((float4*)h)[i] = o;
}

// ---------------------------------------------------------------- attention prep
// per (b,n,h) wave: inv=1/sq (in place over sq), qinv=q*inv, skk=sk+k^2 (in place),
// c = sum(q^2*inv + log sq), d = sum(log sk)
__global__ __launch_bounds__(64) void prep_k(
    const float* __restrict__ qm, const float* __restrict__ km,
    float* __restrict__ sqm, float* __restrict__ skm,
    float* __restrict__ qinvm, float* __restrict__ cvec, float* __restrict__ dvec)
{
    const int blk = blockIdx.x;     // (b*NN+n)*HH + h
    const int bn = blk >> 3, h = blk & 7;
    const int d = threadIdx.x;
    const long idx = (long)bn*KK + h*DHh + d;
    float sq = sqm[idx] + 1e-8f;
    float inv = 1.f/sq;
    float qv = qm[idx];
    float qi = qv*inv;
    sqm[idx] = inv;
    qinvm[idx] = qi;
    float sk = skm[idx] + 1e-8f;
    float kv = km[idx];
    skm[idx] = sk + kv*kv;
    float cv = qv*qi + __logf(sq);
    float dv = __logf(sk);
    #pragma unroll
    for (int o=32;o>0;o>>=1){ cv += __shfl_down(cv,o); dv += __shfl_down(dv,o); }
    if (d==0){
        int b = bn / NN, n = bn % NN;
        int o = (b*HH + h)*NN + n;
        cvec[o] = cv; dvec[o] = dv;
    }
}

// ---------------------------------------------------------------- transpose (B,N,H*64) -> (B,H,128,N) slab
// writes 64 d-rows into cmb at d-offset dslot (0 for skk, 64 for k)
__global__ __launch_bounds__(256) void transpose_hd_k(
    const float* __restrict__ src, float* __restrict__ dst, int dslot)
{
    __shared__ float t[64][65];
    const int n0 = blockIdx.x * 64;
    const int h = blockIdx.y, b = blockIdx.z;
    const int tid = threadIdx.x;
    const int c4 = (tid & 15) * 4;
    const int r0 = tid >> 4;             // 0..15
    for (int rr = r0; rr < 64; rr += 16){
        float4 v = *(const float4*)(src + (size_t)(b*NN + n0 + rr)*KK + h*DHh + c4);
        t[c4+0][rr] = v.x; t[c4+1][rr] = v.y; t[c4+2][rr] = v.z; t[c4+3][rr] = v.w;
    }
    __syncthreads();
    for (int dd = r0; dd < 64; dd += 16){
        float4 v = make_float4(t[dd][c4+0], t[dd][c4+1], t[dd][c4+2], t[dd][c4+3]);
        *(float4*)(dst + ((size_t)(b*HH + h)*128 + dslot + dd)*NN + n0 + c4) = v;
    }
}

// ---------------------------------------------------------------- fused KL attention v2
// block = (b,i), 512 threads = 8 waves, wave h owns head h.
// cmb layout: [b,h,128,N] with d=0..63 -> skk^T (coef inv_i), d=64..127 -> k^T (coef -2*qinv_i).
// scores/softmax entirely wave-local (shfl); one barrier before cross-head beta_m.
__global__ __launch_bounds__(512) void attn2_k(
    const float* __restrict__ invm, const float* __restrict__ qinvm,
    const float* __restrict__ cmb, const float* __restrict__ vm,
    const float* __restrict__ cvec, const float* __restrict__ dvec,
    float* __restrict__ outp, float* __restrict__ betam)
{
    __shared__ float s_beta[HH][NN];   // 32 KB
    __shared__ float s_cf[HH][128];    // 4 KB
    const int tid = threadIdx.x;
    const int h = tid >> 6, lane = tid & 63;
    const int b = blockIdx.x / NN, i = blockIdx.x % NN;
    const int L = i + 1;
    const long rowi = (long)(b*NN+i)*KK + h*DHh + lane;
    s_cf[h][lane]    = invm[rowi];
    s_cf[h][64+lane] = -2.f*qinvm[rowi];
    __syncthreads();
    const float ci = cvec[(b*HH+h)*NN + i];
    const float* dptr = dvec + (b*HH+h)*NN;
    const float* cbase = cmb + (long)(b*HH+h)*128*NN;

    float sc_loc[16];
    float lmax = -3.0e38f;
    int t = 0;
    for (int j0 = 2*lane; j0 < L; j0 += 128, t += 2){
        const float* cp = cbase + j0;
        float ax=0.f, ay=0.f, bx=0.f, by=0.f;
        #pragma unroll 8
        for (int d = 0; d < 128; d += 2){
            float c0 = s_cf[h][d], c1 = s_cf[h][d+1];
            float2 v0 = *(const float2*)(cp + (long)d*NN);
            float2 v1 = *(const float2*)(cp + (long)(d+1)*NN);
            ax = fmaf(c0, v0.x, ax); ay = fmaf(c0, v0.y, ay);
            bx = fmaf(c1, v1.x, bx); by = fmaf(c1, v1.y, by);
        }
        float s0 = -0.5f*((ax+bx) + ci - dptr[j0] - 64.f);
        float s1 = (j0+1 < L) ? -0.5f*((ay+by) + ci - dptr[j0+1] - 64.f) : -3.0e38f;
        sc_loc[t] = s0; sc_loc[t+1] = s1;
        lmax = fmaxf(lmax, fmaxf(s0, s1));
    }
    #pragma unroll
    for (int o=32;o>0;o>>=1) lmax = fmaxf(lmax, __shfl_xor(lmax, o));
    float psum = 0.f;
    t = 0;
    for (int j0 = 2*lane; j0 < L; j0 += 128, t += 2){
        float e0 = __expf(sc_loc[t]   - lmax);
        float e1 = __expf(sc_loc[t+1] - lmax);
        sc_loc[t] = e0; sc_loc[t+1] = e1;
        psum += e0 + e1;
    }
    #pragma unroll
    for (int o=32;o>0;o>>=1) psum += __shfl_xor(psum, o);
    const float isum = 1.f/psum;
    t = 0;
    for (int j0 = 2*lane; j0 < L; j0 += 128, t += 2){
        float2 w2 = make_float2(sc_loc[t]*isum, sc_loc[t+1]*isum);
        *(float2*)&s_beta[h][j0] = w2;
    }

    // PV (wave-local: s_beta[h] written by this wave)
    const float* vb = vm + (long)(b*NN)*KK + h*DHh + lane;
    float o0=0.f,o1=0.f,o2=0.f,o3=0.f;
    int j = 0;
    for (; j+4 <= L; j += 4){
        float w0 = s_beta[h][j], w1 = s_beta[h][j+1];
        float w2 = s_beta[h][j+2], w3 = s_beta[h][j+3];
        o0 = fmaf(w0, vb[(long)(j+0)*KK], o0);
        o1 = fmaf(w1, vb[(long)(j+1)*KK], o1);
        o2 = fmaf(w2, vb[(long)(j+2)*KK], o2);
        o3 = fmaf(w3, vb[(long)(j+3)*KK], o3);
    }
    for (; j < L; ++j) o0 = fmaf(s_beta[h][j], vb[(long)j*KK], o0);
    outp[rowi] = o0+o1+o2+o3;

    __syncthreads();
    const long bmrow = ((long)b*NN + i)*NN;
    for (int jj = tid; jj < NN; jj += 512){
        float s = 0.f;
        if (jj < L){
            #pragma unroll
            for (int h2 = 0; h2 < HH; ++h2) s += s_beta[h2][jj];
            s *= 0.125f;
        }
        betam[bmrow + jj] = s;
    }
}

// ---------------------------------------------------------------- launch
extern "C" void kernel_launch(void* const* d_in, const int* in_sizes, int n_in,
                              void* d_out, int out_size, void* d_ws, size_t ws_size,
                              hipStream_t stream) {
    const float* mu_q    = (const float*)d_in[0];
    const float* sigma_q = (const float*)d_in[1];
    const float* phi     = (const float*)d_in[2];
    const float* gen     = (const float*)d_in[3];
    // d_in[4] = causal mask (reconstructed analytically)
    const float* mu_prior= (const float*)d_in[5];
    const float* Wq = (const float*)d_in[6];
    const float* Wk = (const float*)d_in[7];
    const float* Wv = (const float*)d_in[8];
    const float* Wo = (const float*)d_in[9];
    const float* g1 = (const float*)d_in[10];
    const float* be1= (const float*)d_in[11];
    const float* g2 = (const float*)d_in[12];
    const float* be2= (const float*)d_in[13];
    const float* W1 = (const float*)d_in[14];
    const float* bh1= (const float*)d_in[15];
    const float* W2 = (const float*)d_in[16];
    const float* bh2= (const float*)d_in[17];
    const float* lr = (const float*)d_in[18];
    float* out = (float*)d_out;

    float* w = (float*)d_ws;
    size_t off = 0;
    auto alloc = [&](size_t n){ float* p = w + off; off += n; return p; };
    float* GTb  = alloc((size_t)KK*3*KK);      // 786432
    float* Wq2b = alloc((size_t)KK*KK);
    float* Wk2b = alloc((size_t)KK*KK);
    float* Xb   = alloc((size_t)BN*KK);        // mu_n -> mu_g -> attn_out
    float* Tb   = alloc((size_t)BN*3*KK);      // transport temp
    float* A1b  = alloc((size_t)BN*KK);        // a1 -> wo_out -> bmh
    float* A2b  = alloc((size_t)BN*KK);        // a2 -> a1'
    float* Qb   = alloc((size_t)BN*KK);        // q  -> a2'
    float* Kb   = alloc((size_t)BN*KK);        // k  -> mu_res
    float* Vb   = alloc((size_t)BN*KK);        // v  -> mu_n2
    float* SQb  = alloc((size_t)BN*KK);        // sq -> inv -> h
    float* SKb  = alloc((size_t)BN*KK);        // sk -> skk -> drive
    float* QIb  = alloc((size_t)BN*KK);        // qinv
    float* Cb_  = alloc((size_t)BB*HH*NN);
    float* Db_  = alloc((size_t)BB*HH*NN);
    float* BMb  = alloc((size_t)BB*NN*NN);     // beta_m
    float* Zb   = alloc((size_t)BN*HIDd);      // gelu hidden
    float* CMB  = alloc((size_t)BB*HH*128*NN); // combined skk^T/k^T, d-major

    auto gemm = [&](const float* A, const float* Bm, float* C, int M, int Kc, int Nc,
                    const float* bias, int act){
        dim3 g(Nc/64, M/64, 1);
        gemm_k<<<g, 256, 0, stream>>>(A, Bm, C, M, Kc, Nc, 0L, 0L, 0L, bias, act);
    };

    // phase 0: weights prep
    square_k<<<(KK*KK+255)/256, 256, 0, stream>>>(Wq, Wq2b, KK*KK);
    square_k<<<(KK*KK+255)/256, 256, 0, stream>>>(Wk, Wk2b, KK*KK);
    build_gt_k<<<(KK*3*KK+255)/256, 256, 0, stream>>>(gen, GTb);

    // phase A: LN1 + forward transport
    ln_k<<<BN, 256, 0, stream>>>(mu_q, g1, be1, Xb);
    gemm(Xb, GTb, Tb, BN, KK, 3*KK, nullptr, 0);
    combine_k<<<BN*KK/4/256, 256, 0, stream>>>(Tb, phi, A1b, 1.f);
    gemm(A1b, GTb, Tb, BN, KK, 3*KK, nullptr, 0);
    combine_k<<<BN*KK/4/256, 256, 0, stream>>>(Tb, phi, A2b, 1.f);
    tfinal_k<<<BN*KK/4/256, 256, 0, stream>>>(Xb, A1b, A2b, nullptr, Xb);   // mu_g

    // phase B: projections + attention prep
    gemm(Xb, Wq, Qb, BN, KK, KK, nullptr, 0);
    gemm(Xb, Wk, Kb, BN, KK, KK, nullptr, 0);
    gemm(Xb, Wv, Vb, BN, KK, KK, nullptr, 0);
    gemm(sigma_q, Wq2b, SQb, BN, KK, KK, nullptr, 0);
    gemm(sigma_q, Wk2b, SKb, BN, KK, KK, nullptr, 0);
    prep_k<<<BN*HH, 64, 0, stream>>>(Qb, Kb, SQb, SKb, QIb, Cb_, Db_);
    {
        dim3 tg(NN/64, HH, BB);
        transpose_hd_k<<<tg, 256, 0, stream>>>(SKb, CMB, 0);   // skk^T
        transpose_hd_k<<<tg, 256, 0, stream>>>(Kb,  CMB, 64);  // k^T
    }

    // phase C: fused attention (writes attn_out into Xb, beta_m into BMb)
    attn2_k<<<BN, 512, 0, stream>>>(SQb, QIb, CMB, Vb, Cb_, Db_, Xb, BMb);

    // phase D: output proj + back transport + residual + LN2
    gemm(Xb, Wo, A1b, BN, KK, KK, nullptr, 0);                               // wo_out
    gemm(A1b, GTb, Tb, BN, KK, 3*KK, nullptr, 0);
    combine_k<<<BN*KK/4/256, 256, 0, stream>>>(Tb, phi, A2b, -1.f);          // a1'
    gemm(A2b, GTb, Tb, BN, KK, 3*KK, nullptr, 0);
    combine_k<<<BN*KK/4/256, 256, 0, stream>>>(Tb, phi, Qb, -1.f);           // a2'
    tfinal_k<<<BN*KK/4/256, 256, 0, stream>>>(A1b, A2b, Qb, mu_q, Kb);       // mu_res
    ln_k<<<BN, 256, 0, stream>>>(Kb, g2, be2, Vb);                           // mu_n2
    copy_k<<<BN*KK/4/256, 256, 0, stream>>>(Vb, SQb, BN*KK/4);               // h = mu_n2

    // phase E: 2 VFE iterations
    for (int it=0; it<2; ++it){
        gemm(SQb, W1, Zb, BN, KK, HIDd, bh1, 1);                             // gelu(h@W1+b1)
        gemm(Zb, W2, SKb, BN, HIDd, KK, bh2, 0);                             // drive
        {   // bmh = beta_m @ h   (batched over B)
            dim3 g(KK/64, NN/64, BB);
            gemm_k<<<g, 256, 0, stream>>>(BMb, SQb, A1b, NN, NN, KK,
                                          (long)NN*NN, (long)NN*KK, (long)NN*KK,
                                          nullptr, 0);
        }
        ffn_update_k<<<BN*KK/4/256, 256, 0, stream>>>(SQb, SKb, A1b, mu_prior, lr);
    }

    // phase F: outputs
    final_k<<<BN*KK/4/256, 256, 0, stream>>>(Kb, SQb, Vb, out);              // mu_out
    copy_k<<<BN*KK/4/256, 256, 0, stream>>>(sigma_q, out + (size_t)BN*KK, BN*KK/4);
    copy_k<<<(BN*3/4+255)/256, 256, 0, stream>>>(phi, out + 2*(size_t)BN*KK, BN*3/4);

    (void)in_sizes; (void)n_in; (void)out_size; (void)ws_size;
}

// Round 3
// 1673.141 us; speedup vs baseline: 2.7203x; 1.3097x over previous
//
#include <hip/hip_runtime.h>
#include <math.h>

#define BB 4
#define NN 1024
#define KK 512
#define HH 8
#define DHh 64
#define HIDd 2048
#define BN (BB*NN)

typedef unsigned short u16;
typedef __attribute__((ext_vector_type(8))) short bf16x8;
typedef __attribute__((ext_vector_type(4))) float f32x4;

// ---------------------------------------------------------------- helpers
__device__ __forceinline__ float gelu_tanh(float x){
    float x3 = x*x*x;
    float t = tanhf(0.7978845608028654f*(x + 0.044715f*x3));
    return 0.5f*x*(1.0f+t);
}
__device__ __forceinline__ u16 f2bf(float x){
    unsigned int u = __float_as_uint(x);
    unsigned int r = (u + 0x7fffu + ((u>>16)&1u)) >> 16;
    return (u16)r;
}
__device__ __forceinline__ float bf2f(u16 b){
    return __uint_as_float(((unsigned int)b)<<16);
}
__device__ __forceinline__ void gload16(const void* g, void* l){
    __builtin_amdgcn_global_load_lds((__attribute__((address_space(1))) void*)g,
                                     (__attribute__((address_space(3))) void*)l, 16, 0, 0);
}

// ---------------------------------------------------------------- split conversions
__global__ __launch_bounds__(256) void split_k(const float* __restrict__ src,
                                               u16* __restrict__ hi, u16* __restrict__ lo, long n){
    long i = (long)blockIdx.x*256 + threadIdx.x;
    if (i >= n) return;
    float v = src[i];
    u16 h = f2bf(v);
    hi[i] = h;
    lo[i] = f2bf(v - bf2f(h));
}

// src [Kc][Nc] (row-major, +batch stride sS) -> dst [Nc][Kc] hi/lo bf16 (+batch sD). square opt.
__global__ __launch_bounds__(256) void split_t_k(
    const float* __restrict__ src, u16* __restrict__ hi, u16* __restrict__ lo,
    int Kc, int Nc, long sS, long sD, int square)
{
    __shared__ float t[32][33];
    const int n0 = blockIdx.x*32, k0 = blockIdx.y*32, bz = blockIdx.z;
    const float* S = src + (long)bz*sS;
    const int tx = threadIdx.x & 31, ty = threadIdx.x >> 5;
    for (int r = ty; r < 32; r += 8){
        float v = S[(long)(k0+r)*Nc + n0+tx];
        if (square) v *= v;
        t[r][tx] = v;
    }
    __syncthreads();
    for (int r = ty; r < 32; r += 8){
        float v = t[tx][r];
        u16 h = f2bf(v);
        long o = (long)bz*sD + (long)(n0+r)*Kc + k0 + tx;
        hi[o] = h;
        lo[o] = f2bf(v - bf2f(h));
    }
}

// ---------------------------------------------------------------- MFMA GEMM (split bf16, ~fp32 acc)
// C = (Ah+Al)(Bh+Bl) ~= AhBh + AhBl + AlBh.  A: [M][K] row-major bf16 hi/lo.
// B: [N][K] row-major (i.e. B^T) bf16 hi/lo.  C: fp32 [M][N]. optional bias+gelu, batch strides.
__global__ __launch_bounds__(256) void gemm_mfma_k(
    const u16* __restrict__ Ah, const u16* __restrict__ Al,
    const u16* __restrict__ Bh, const u16* __restrict__ Bl,
    float* __restrict__ C, int M, int Kc, int Nc,
    long sA, long sB, long sC, const float* __restrict__ bias, int act)
{
    __shared__ u16 sAh[128*32], sAl[128*32], sBh[128*32], sBl[128*32];  // 32 KB
    const int bz = blockIdx.z;
    const u16* gAh = Ah + (long)bz*sA;
    const u16* gAl = Al + (long)bz*sA;
    const u16* gBh = Bh + (long)bz*sB;
    const u16* gBl = Bl + (long)bz*sB;
    float* Cb = C + (long)bz*sC;
    const int tid = threadIdx.x;
    const int wave = tid >> 6, lane = tid & 63;
    const int quad = lane >> 4, r16 = lane & 15;
    const int m0 = blockIdx.y*128, n0 = blockIdx.x*128;
    const int wm = (wave>>1)*64, wn = (wave&1)*64;

    f32x4 acc[4][4];
    #pragma unroll
    for (int i=0;i<4;i++)
        #pragma unroll
        for (int j=0;j<4;j++) acc[i][j] = (f32x4){0.f,0.f,0.f,0.f};

    for (int k0 = 0; k0 < Kc; k0 += 32){
        __syncthreads();
        #pragma unroll
        for (int half=0; half<2; ++half){
            int c = half*256 + tid;          // tid = wave*64+lane: lds dest = uniform + lane*16
            int row = c >> 2, kg = (c & 3)*8;
            long ga = (long)(m0+row)*Kc + k0 + kg;
            long gb = (long)(n0+row)*Kc + k0 + kg;
            gload16(gAh+ga, &sAh[c*8]);
            gload16(gAl+ga, &sAl[c*8]);
            gload16(gBh+gb, &sBh[c*8]);
            gload16(gBl+gb, &sBl[c*8]);
        }
        __syncthreads();
        bf16x8 afh[4], afl[4], bfh[4], bfl[4];
        #pragma unroll
        for (int i=0;i<4;i++){
            afh[i] = *(const bf16x8*)&sAh[(wm+i*16+r16)*32 + quad*8];
            afl[i] = *(const bf16x8*)&sAl[(wm+i*16+r16)*32 + quad*8];
            bfh[i] = *(const bf16x8*)&sBh[(wn+i*16+r16)*32 + quad*8];
            bfl[i] = *(const bf16x8*)&sBl[(wn+i*16+r16)*32 + quad*8];
        }
        #pragma unroll
        for (int i=0;i<4;i++)
            #pragma unroll
            for (int j=0;j<4;j++){
                acc[i][j] = __builtin_amdgcn_mfma_f32_16x16x32_bf16(afh[i], bfh[j], acc[i][j], 0,0,0);
                acc[i][j] = __builtin_amdgcn_mfma_f32_16x16x32_bf16(afh[i], bfl[j], acc[i][j], 0,0,0);
                acc[i][j] = __builtin_amdgcn_mfma_f32_16x16x32_bf16(afl[i], bfh[j], acc[i][j], 0,0,0);
            }
    }
    // epilogue: C/D layout col=lane&15, row=quad*4+reg
    #pragma unroll
    for (int i=0;i<4;i++){
        #pragma unroll
        for (int j=0;j<4;j++){
            int gc = n0 + wn + j*16 + r16;
            float bv = bias ? bias[gc] : 0.f;
            #pragma unroll
            for (int r=0;r<4;r++){
                long gr = m0 + wm + i*16 + quad*4 + r;
                float v = acc[i][j][r] + bv;
                if (act) v = gelu_tanh(v);
                Cb[gr*Nc + gc] = v;
            }
        }
    }
}

// ---------------------------------------------------------------- LayerNorm (rows of 512)
__global__ __launch_bounds__(256) void ln_k(
    const float* __restrict__ x, const float* __restrict__ g,
    const float* __restrict__ be, float* __restrict__ y)
{
    __shared__ float sh[8];
    const int r = blockIdx.x, tid = threadIdx.x;
    const float* xr = x + (long)r*KK;
    float2 v = *(const float2*)(xr + tid*2);
    float s = v.x+v.y, s2 = v.x*v.x+v.y*v.y;
    #pragma unroll
    for (int o=32;o>0;o>>=1){ s += __shfl_down(s,o); s2 += __shfl_down(s2,o); }
    if ((tid&63)==0){ sh[tid>>6]=s; sh[4+(tid>>6)]=s2; }
    __syncthreads();
    s  = sh[0]+sh[1]+sh[2]+sh[3];
    s2 = sh[4]+sh[5]+sh[6]+sh[7];
    const float mean = s*(1.f/KK);
    const float var  = s2*(1.f/KK) - mean*mean;
    const float rs = rsqrtf(var + 1e-5f);
    float2 gg = *(const float2*)(g + tid*2);
    float2 bb = *(const float2*)(be + tid*2);
    float2 o;
    o.x = (v.x-mean)*rs*gg.x + bb.x;
    o.y = (v.y-mean)*rs*gg.y + bb.y;
    *(float2*)(y + (long)r*KK + tid*2) = o;
}

// ---------------------------------------------------------------- small elementwise kernels
__global__ void combine_k(const float* __restrict__ t, const float* __restrict__ phi,
                          float* __restrict__ a, float sign){
    int idx = blockIdx.x*256 + threadIdx.x;
    if (idx >= BN*KK/4) return;
    int r = idx >> 7;
    int c4 = (idx & 127) << 2;
    const float* ph = phi + r*3;
    float p0 = sign*ph[0], p1 = sign*ph[1], p2 = sign*ph[2];
    const float* tr = t + (long)r*(3*KK);
    float4 t0 = *(const float4*)(tr + c4);
    float4 t1 = *(const float4*)(tr + KK + c4);
    float4 t2 = *(const float4*)(tr + 2*KK + c4);
    float4 o;
    o.x = p0*t0.x + p1*t1.x + p2*t2.x;
    o.y = p0*t0.y + p1*t1.y + p2*t2.y;
    o.z = p0*t0.z + p1*t1.z + p2*t2.z;
    o.w = p0*t0.w + p1*t1.w + p2*t2.w;
    *(float4*)(a + (long)r*KK + c4) = o;
}
__global__ void tfinal_k(const float* __restrict__ x, const float* __restrict__ a1,
                         const float* __restrict__ a2, const float* __restrict__ res,
                         float* __restrict__ out){
    int i = blockIdx.x*256 + threadIdx.x;
    if (i >= BN*KK/4) return;
    float4 xv = ((const float4*)x)[i];
    float4 v1 = ((const float4*)a1)[i];
    float4 v2 = ((const float4*)a2)[i];
    float4 o;
    o.x = xv.x + v1.x + 0.5f*v2.x;
    o.y = xv.y + v1.y + 0.5f*v2.y;
    o.z = xv.z + v1.z + 0.5f*v2.z;
    o.w = xv.w + v1.w + 0.5f*v2.w;
    if (res){ float4 rv = ((const float4*)res)[i]; o.x+=rv.x; o.y+=rv.y; o.z+=rv.z; o.w+=rv.w; }
    ((float4*)out)[i] = o;
}
__global__ void copy_k(const float* __restrict__ s, float* __restrict__ d, int n4){
    int i = blockIdx.x*256 + threadIdx.x;
    if (i < n4) ((float4*)d)[i] = ((const float4*)s)[i];
}
__global__ void final_k(const float* __restrict__ a, const float* __restrict__ b,
                        const float* __restrict__ c, float* __restrict__ out){
    int i = blockIdx.x*256 + threadIdx.x;
    if (i >= BN*KK/4) return;
    float4 av = ((const float4*)a)[i], bv = ((const float4*)b)[i], cv = ((const float4*)c)[i];
    float4 o;
    o.x = av.x + bv.x - cv.x; o.y = av.y + bv.y - cv.y;
    o.z = av.z + bv.z - cv.z; o.w = av.w + bv.w - cv.w;
    ((float4*)out)[i] = o;
}
__global__ void ffn_update_k(float* __restrict__ h, const float* __restrict__ drive,
                             const float* __restrict__ bmh, const float* __restrict__ mup,
                             const float* __restrict__ lr){
    int i = blockIdx.x*256 + threadIdx.x;
    if (i >= BN*KK/4) return;
    const float lrv = *lr;
    float4 hv = ((float4*)h)[i];
    float4 dv = ((const float4*)drive)[i];
    float4 bv = ((const float4*)bmh)[i];
    float4 pv = ((const float4*)mup)[i];
    float4 o;
    o.x = hv.x + lrv*(dv.x - (1e-3f*(hv.x-pv.x) + 1.0f*(hv.x-bv.x)));
    o.y = hv.y + lrv*(dv.y - (1e-3f*(hv.y-pv.y) + 1.0f*(hv.y-bv.y)));
    o.z = hv.z + lrv*(dv.z - (1e-3f*(hv.z-pv.z) + 1.0f*(hv.z-bv.z)));
    o.w = hv.w + lrv*(dv.w - (1e-3f*(hv.w-pv.w) + 1.0f*(hv.w-bv.w)));
    ((float4*)h)[i] = o;
}

// ---------------------------------------------------------------- attention prep
__global__ __launch_bounds__(64) void prep_k(
    const float* __restrict__ qm, const float* __restrict__ km,
    float* __restrict__ sqm, float* __restrict__ skm,
    float* __restrict__ qinvm, float* __restrict__ cvec, float* __restrict__ dvec)
{
    const int blk = blockIdx.x;
    const int bn = blk >> 3, h = blk & 7;
    const int d = threadIdx.x;
    const long idx = (long)bn*KK + h*DHh + d;
    float sq = sqm[idx] + 1e-8f;
    float inv = 1.f/sq;
    float qv = qm[idx];
    float qi = qv*inv;
    sqm[idx] = inv;
    qinvm[idx] = qi;
    float sk = skm[idx] + 1e-8f;
    float kv = km[idx];
    skm[idx] = sk + kv*kv;
    float cv = qv*qi + __logf(sq);
    float dv = __logf(sk);
    #pragma unroll
    for (int o=32;o>0;o>>=1){ cv += __shfl_down(cv,o); dv += __shfl_down(dv,o); }
    if (d==0){
        int b = bn / NN, n = bn % NN;
        int o = (b*HH + h)*NN + n;
        cvec[o] = cv; dvec[o] = dv;
    }
}

// ---------------------------------------------------------------- transpose (B,N,H*64) -> (B,H,128,N)
__global__ __launch_bounds__(256) void transpose_hd_k(
    const float* __restrict__ src, float* __restrict__ dst, int dslot)
{
    __shared__ float t[64][65];
    const int n0 = blockIdx.x * 64;
    const int h = blockIdx.y, b = blockIdx.z;
    const int tid = threadIdx.x;
    const int c4 = (tid & 15) * 4;
    const int r0 = tid >> 4;
    for (int rr = r0; rr < 64; rr += 16){
        float4 v = *(const float4*)(src + (size_t)(b*NN + n0 + rr)*KK + h*DHh + c4);
        t[c4+0][rr] = v.x; t[c4+1][rr] = v.y; t[c4+2][rr] = v.z; t[c4+3][rr] = v.w;
    }
    __syncthreads();
    for (int dd = r0; dd < 64; dd += 16){
        float4 v = make_float4(t[dd][c4+0], t[dd][c4+1], t[dd][c4+2], t[dd][c4+3]);
        *(float4*)(dst + ((size_t)(b*HH + h)*128 + dslot + dd)*NN + n0 + c4) = v;
    }
}

// ---------------------------------------------------------------- fused KL attention
__global__ __launch_bounds__(512) void attn2_k(
    const float* __restrict__ invm, const float* __restrict__ qinvm,
    const float* __restrict__ cmb, const float* __restrict__ vm,
    const float* __restrict__ cvec, const float* __restrict__ dvec,
    float* __restrict__ outp, float* __restrict__ betam)
{
    __shared__ float s_beta[HH][NN];
    __shared__ float s_cf[HH][128];
    const int tid = threadIdx.x;
    const int h = tid >> 6, lane = tid & 63;
    const int b = blockIdx.x / NN, i = blockIdx.x % NN;
    const int L = i + 1;
    const long rowi = (long)(b*NN+i)*KK + h*DHh + lane;
    s_cf[h][lane]    = invm[rowi];
    s_cf[h][64+lane] = -2.f*qinvm[rowi];
    __syncthreads();
    const float ci = cvec[(b*HH+h)*NN + i];
    const float* dptr = dvec + (b*HH+h)*NN;
    const float* cbase = cmb + (long)(b*HH+h)*128*NN;

    float sc_loc[16];
    float lmax = -3.0e38f;
    int t = 0;
    for (int j0 = 2*lane; j0 < L; j0 += 128, t += 2){
        const float* cp = cbase + j0;
        float ax=0.f, ay=0.f, bx=0.f, by=0.f;
        #pragma unroll 8
        for (int d = 0; d < 128; d += 2){
            float c0 = s_cf[h][d], c1 = s_cf[h][d+1];
            float2 v0 = *(const float2*)(cp + (long)d*NN);
            float2 v1 = *(const float2*)(cp + (long)(d+1)*NN);
            ax = fmaf(c0, v0.x, ax); ay = fmaf(c0, v0.y, ay);
            bx = fmaf(c1, v1.x, bx); by = fmaf(c1, v1.y, by);
        }
        float s0 = -0.5f*((ax+bx) + ci - dptr[j0] - 64.f);
        float s1 = (j0+1 < L) ? -0.5f*((ay+by) + ci - dptr[j0+1] - 64.f) : -3.0e38f;
        sc_loc[t] = s0; sc_loc[t+1] = s1;
        lmax = fmaxf(lmax, fmaxf(s0, s1));
    }
    #pragma unroll
    for (int o=32;o>0;o>>=1) lmax = fmaxf(lmax, __shfl_xor(lmax, o));
    float psum = 0.f;
    t = 0;
    for (int j0 = 2*lane; j0 < L; j0 += 128, t += 2){
        float e0 = __expf(sc_loc[t]   - lmax);
        float e1 = __expf(sc_loc[t+1] - lmax);
        sc_loc[t] = e0; sc_loc[t+1] = e1;
        psum += e0 + e1;
    }
    #pragma unroll
    for (int o=32;o>0;o>>=1) psum += __shfl_xor(psum, o);
    const float isum = 1.f/psum;
    t = 0;
    for (int j0 = 2*lane; j0 < L; j0 += 128, t += 2){
        float2 w2 = make_float2(sc_loc[t]*isum, sc_loc[t+1]*isum);
        *(float2*)&s_beta[h][j0] = w2;
    }

    const float* vb = vm + (long)(b*NN)*KK + h*DHh + lane;
    float o0=0.f,o1=0.f,o2=0.f,o3=0.f;
    int j = 0;
    for (; j+4 <= L; j += 4){
        float w0 = s_beta[h][j], w1 = s_beta[h][j+1];
        float w2 = s_beta[h][j+2], w3 = s_beta[h][j+3];
        o0 = fmaf(w0, vb[(long)(j+0)*KK], o0);
        o1 = fmaf(w1, vb[(long)(j+1)*KK], o1);
        o2 = fmaf(w2, vb[(long)(j+2)*KK], o2);
        o3 = fmaf(w3, vb[(long)(j+3)*KK], o3);
    }
    for (; j < L; ++j) o0 = fmaf(s_beta[h][j], vb[(long)j*KK], o0);
    outp[rowi] = o0+o1+o2+o3;

    __syncthreads();
    const long bmrow = ((long)b*NN + i)*NN;
    for (int jj = tid; jj < NN; jj += 512){
        float s = 0.f;
        if (jj < L){
            #pragma unroll
            for (int h2 = 0; h2 < HH; ++h2) s += s_beta[h2][jj];
            s *= 0.125f;
        }
        betam[bmrow + jj] = s;
    }
}

// ---------------------------------------------------------------- launch
extern "C" void kernel_launch(void* const* d_in, const int* in_sizes, int n_in,
                              void* d_out, int out_size, void* d_ws, size_t ws_size,
                              hipStream_t stream) {
    const float* mu_q    = (const float*)d_in[0];
    const float* sigma_q = (const float*)d_in[1];
    const float* phi     = (const float*)d_in[2];
    const float* gen     = (const float*)d_in[3];
    const float* mu_prior= (const float*)d_in[5];
    const float* Wq = (const float*)d_in[6];
    const float* Wk = (const float*)d_in[7];
    const float* Wv = (const float*)d_in[8];
    const float* Wo = (const float*)d_in[9];
    const float* g1 = (const float*)d_in[10];
    const float* be1= (const float*)d_in[11];
    const float* g2 = (const float*)d_in[12];
    const float* be2= (const float*)d_in[13];
    const float* W1 = (const float*)d_in[14];
    const float* bh1= (const float*)d_in[15];
    const float* W2 = (const float*)d_in[16];
    const float* bh2= (const float*)d_in[17];
    const float* lr = (const float*)d_in[18];
    float* out = (float*)d_out;

    float* w = (float*)d_ws;
    size_t off = 0;
    auto alloc = [&](size_t n){ float* p = w + off; off += (n+3)&~(size_t)3; return p; };
    auto ualloc = [&](size_t n){ return (u16*)alloc((n+1)/2); };

    // fp32 buffers
    float* Xb   = alloc((size_t)BN*KK);        // mu_n -> mu_g -> attn_out
    float* Tb   = alloc((size_t)BN*3*KK);      // transport temp
    float* A1b  = alloc((size_t)BN*KK);
    float* A2b  = alloc((size_t)BN*KK);
    float* Qb   = alloc((size_t)BN*KK);
    float* Kb   = alloc((size_t)BN*KK);
    float* Vb   = alloc((size_t)BN*KK);
    float* SQb  = alloc((size_t)BN*KK);
    float* SKb  = alloc((size_t)BN*KK);
    float* QIb  = alloc((size_t)BN*KK);
    float* Cb_  = alloc((size_t)BB*HH*NN);
    float* Db_  = alloc((size_t)BB*HH*NN);
    float* BMb  = alloc((size_t)BB*NN*NN);     // beta_m
    float* Zb   = alloc((size_t)BN*HIDd);
    float* CMB  = alloc((size_t)BB*HH*128*NN);
    // bf16 split buffers
    u16* GTh = ualloc((size_t)3*KK*KK); u16* GTl = ualloc((size_t)3*KK*KK);   // gen as-is = (x@GT) B^T
    u16* WqTh= ualloc((size_t)KK*KK);   u16* WqTl= ualloc((size_t)KK*KK);
    u16* WkTh= ualloc((size_t)KK*KK);   u16* WkTl= ualloc((size_t)KK*KK);
    u16* WvTh= ualloc((size_t)KK*KK);   u16* WvTl= ualloc((size_t)KK*KK);
    u16* WoTh= ualloc((size_t)KK*KK);   u16* WoTl= ualloc((size_t)KK*KK);
    u16* Wq2h= ualloc((size_t)KK*KK);   u16* Wq2l= ualloc((size_t)KK*KK);
    u16* Wk2h= ualloc((size_t)KK*KK);   u16* Wk2l= ualloc((size_t)KK*KK);
    u16* W1Th= ualloc((size_t)KK*HIDd); u16* W1Tl= ualloc((size_t)KK*HIDd);
    u16* W2Th= ualloc((size_t)KK*HIDd); u16* W2Tl= ualloc((size_t)KK*HIDd);
    u16* AH  = ualloc((size_t)BN*HIDd); u16* AL  = ualloc((size_t)BN*HIDd);   // generic A split
    u16* BMh = ualloc((size_t)BB*NN*NN);u16* BMl = ualloc((size_t)BB*NN*NN);
    u16* HTh = ualloc((size_t)BB*KK*NN);u16* HTl = ualloc((size_t)BB*KK*NN);

    auto gemm = [&](const u16* ah, const u16* al, const u16* bh, const u16* bl,
                    float* C, int M, int Kc, int Nc, long sA, long sB, long sC,
                    const float* bias, int act, int batch){
        dim3 g(Nc/128, M/128, batch);
        gemm_mfma_k<<<g, 256, 0, stream>>>(ah, al, bh, bl, C, M, Kc, Nc, sA, sB, sC, bias, act);
    };
    auto splitA = [&](const float* src, long n){
        split_k<<<(int)((n+255)/256), 256, 0, stream>>>(src, AH, AL, n);
    };

    // ---- weight prep (once) ----
    split_k<<<(3*KK*KK+255)/256, 256, 0, stream>>>(gen, GTh, GTl, (long)3*KK*KK);
    {
        dim3 gq(KK/32, KK/32, 1);
        split_t_k<<<gq, 256, 0, stream>>>(Wq, WqTh, WqTl, KK, KK, 0L, 0L, 0);
        split_t_k<<<gq, 256, 0, stream>>>(Wk, WkTh, WkTl, KK, KK, 0L, 0L, 0);
        split_t_k<<<gq, 256, 0, stream>>>(Wv, WvTh, WvTl, KK, KK, 0L, 0L, 0);
        split_t_k<<<gq, 256, 0, stream>>>(Wo, WoTh, WoTl, KK, KK, 0L, 0L, 0);
        split_t_k<<<gq, 256, 0, stream>>>(Wq, Wq2h, Wq2l, KK, KK, 0L, 0L, 1);
        split_t_k<<<gq, 256, 0, stream>>>(Wk, Wk2h, Wk2l, KK, KK, 0L, 0L, 1);
        dim3 g1g(HIDd/32, KK/32, 1);
        split_t_k<<<g1g, 256, 0, stream>>>(W1, W1Th, W1Tl, KK, HIDd, 0L, 0L, 0);
        dim3 g2g(KK/32, HIDd/32, 1);
        split_t_k<<<g2g, 256, 0, stream>>>(W2, W2Th, W2Tl, HIDd, KK, 0L, 0L, 0);
    }

    // ---- phase A: LN1 + forward transport ----
    ln_k<<<BN, 256, 0, stream>>>(mu_q, g1, be1, Xb);
    splitA(Xb, (long)BN*KK);
    gemm(AH, AL, GTh, GTl, Tb, BN, KK, 3*KK, 0,0,0, nullptr, 0, 1);
    combine_k<<<BN*KK/4/256, 256, 0, stream>>>(Tb, phi, A1b, 1.f);
    splitA(A1b, (long)BN*KK);
    gemm(AH, AL, GTh, GTl, Tb, BN, KK, 3*KK, 0,0,0, nullptr, 0, 1);
    combine_k<<<BN*KK/4/256, 256, 0, stream>>>(Tb, phi, A2b, 1.f);
    tfinal_k<<<BN*KK/4/256, 256, 0, stream>>>(Xb, A1b, A2b, nullptr, Xb);   // mu_g

    // ---- phase B: projections + attention prep ----
    splitA(Xb, (long)BN*KK);
    gemm(AH, AL, WqTh, WqTl, Qb, BN, KK, KK, 0,0,0, nullptr, 0, 1);
    gemm(AH, AL, WkTh, WkTl, Kb, BN, KK, KK, 0,0,0, nullptr, 0, 1);
    gemm(AH, AL, WvTh, WvTl, Vb, BN, KK, KK, 0,0,0, nullptr, 0, 1);
    splitA(sigma_q, (long)BN*KK);
    gemm(AH, AL, Wq2h, Wq2l, SQb, BN, KK, KK, 0,0,0, nullptr, 0, 1);
    gemm(AH, AL, Wk2h, Wk2l, SKb, BN, KK, KK, 0,0,0, nullptr, 0, 1);
    prep_k<<<BN*HH, 64, 0, stream>>>(Qb, Kb, SQb, SKb, QIb, Cb_, Db_);
    {
        dim3 tg(NN/64, HH, BB);
        transpose_hd_k<<<tg, 256, 0, stream>>>(SKb, CMB, 0);
        transpose_hd_k<<<tg, 256, 0, stream>>>(Kb,  CMB, 64);
    }

    // ---- phase C: fused attention ----
    attn2_k<<<BN, 512, 0, stream>>>(SQb, QIb, CMB, Vb, Cb_, Db_, Xb, BMb);

    // ---- phase D: output proj + back transport + residual + LN2 ----
    splitA(Xb, (long)BN*KK);
    gemm(AH, AL, WoTh, WoTl, A1b, BN, KK, KK, 0,0,0, nullptr, 0, 1);        // wo_out
    splitA(A1b, (long)BN*KK);
    gemm(AH, AL, GTh, GTl, Tb, BN, KK, 3*KK, 0,0,0, nullptr, 0, 1);
    combine_k<<<BN*KK/4/256, 256, 0, stream>>>(Tb, phi, A2b, -1.f);         // a1'
    splitA(A2b, (long)BN*KK);
    gemm(AH, AL, GTh, GTl, Tb, BN, KK, 3*KK, 0,0,0, nullptr, 0, 1);
    combine_k<<<BN*KK/4/256, 256, 0, stream>>>(Tb, phi, Qb, -1.f);          // a2'
    tfinal_k<<<BN*KK/4/256, 256, 0, stream>>>(A1b, A2b, Qb, mu_q, Kb);      // mu_res
    ln_k<<<BN, 256, 0, stream>>>(Kb, g2, be2, Vb);                          // mu_n2
    copy_k<<<BN*KK/4/256, 256, 0, stream>>>(Vb, SQb, BN*KK/4);              // h = mu_n2

    // beta_m split (constant across iterations)
    split_k<<<(int)(((long)BB*NN*NN+255)/256), 256, 0, stream>>>(BMb, BMh, BMl, (long)BB*NN*NN);

    // ---- phase E: 2 VFE iterations ----
    for (int it=0; it<2; ++it){
        splitA(SQb, (long)BN*KK);                                            // h
        gemm(AH, AL, W1Th, W1Tl, Zb, BN, KK, HIDd, 0,0,0, bh1, 1, 1);        // gelu(h@W1+b1)
        splitA(Zb, (long)BN*HIDd);
        gemm(AH, AL, W2Th, W2Tl, SKb, BN, HIDd, KK, 0,0,0, bh2, 0, 1);       // drive
        {
            dim3 tg(KK/32, NN/32, BB);                                       // h^T per batch
            split_t_k<<<tg, 256, 0, stream>>>(SQb, HTh, HTl, NN, KK,
                                              (long)NN*KK, (long)KK*NN, 0);
        }
        gemm(BMh, BMl, HTh, HTl, A1b, NN, NN, KK,
             (long)NN*NN, (long)KK*NN, (long)NN*KK, nullptr, 0, BB);         // bmh
        ffn_update_k<<<BN*KK/4/256, 256, 0, stream>>>(SQb, SKb, A1b, mu_prior, lr);
    }

    // ---- phase F: outputs ----
    final_k<<<BN*KK/4/256, 256, 0, stream>>>(Kb, SQb, Vb, out);
    copy_k<<<BN*KK/4/256, 256, 0, stream>>>(sigma_q, out + (size_t)BN*KK, BN*KK/4);
    copy_k<<<(BN*3/4+255)/256, 256, 0, stream>>>(phi, out + 2*(size_t)BN*KK, BN*3/4);

    (void)in_sizes; (void)n_in; (void)out_size; (void)ws_size;
}

// Round 4
// 1275.902 us; speedup vs baseline: 3.5672x; 1.3113x over previous
//
#include <hip/hip_runtime.h>
#include <math.h>

#define BB 4
#define NN 1024
#define KK 512
#define HH 8
#define DHh 64
#define HIDd 2048
#define BN (BB*NN)

typedef unsigned short u16;
typedef __attribute__((ext_vector_type(8))) short bf16x8;
typedef __attribute__((ext_vector_type(4))) float f32x4;

// ---------------------------------------------------------------- helpers
__device__ __forceinline__ float gelu_tanh(float x){
    float x3 = x*x*x;
    float t = tanhf(0.7978845608028654f*(x + 0.044715f*x3));
    return 0.5f*x*(1.0f+t);
}
__device__ __forceinline__ u16 f2bf(float x){
    unsigned int u = __float_as_uint(x);
    unsigned int r = (u + 0x7fffu + ((u>>16)&1u)) >> 16;
    return (u16)r;
}
__device__ __forceinline__ float bf2f(u16 b){
    return __uint_as_float(((unsigned int)b)<<16);
}
__device__ __forceinline__ void gload16(const void* g, void* l){
    __builtin_amdgcn_global_load_lds((__attribute__((address_space(1))) void*)g,
                                     (__attribute__((address_space(3))) void*)l, 16, 0, 0);
}

// ---------------------------------------------------------------- split conversions
__global__ __launch_bounds__(256) void split_k(const float* __restrict__ src,
                                               u16* __restrict__ hi, u16* __restrict__ lo, long n){
    long i = (long)blockIdx.x*256 + threadIdx.x;
    if (i >= n) return;
    float v = src[i];
    u16 h = f2bf(v);
    hi[i] = h;
    lo[i] = f2bf(v - bf2f(h));
}

// src [Kc][Nc] (row-major, +batch stride sS) -> dst [Nc][Kc] hi/lo bf16 (+batch sD). square opt.
__global__ __launch_bounds__(256) void split_t_k(
    const float* __restrict__ src, u16* __restrict__ hi, u16* __restrict__ lo,
    int Kc, int Nc, long sS, long sD, int square)
{
    __shared__ float t[32][33];
    const int n0 = blockIdx.x*32, k0 = blockIdx.y*32, bz = blockIdx.z;
    const float* S = src + (long)bz*sS;
    const int tx = threadIdx.x & 31, ty = threadIdx.x >> 5;
    for (int r = ty; r < 32; r += 8){
        float v = S[(long)(k0+r)*Nc + n0+tx];
        if (square) v *= v;
        t[r][tx] = v;
    }
    __syncthreads();
    for (int r = ty; r < 32; r += 8){
        float v = t[tx][r];
        u16 h = f2bf(v);
        long o = (long)bz*sD + (long)(n0+r)*Kc + k0 + tx;
        hi[o] = h;
        lo[o] = f2bf(v - bf2f(h));
    }
}

// ---------------------------------------------------------------- MFMA GEMM (split bf16, ~fp32 acc)
// C = A*B^T.  A: [M][lda] bf16 hi/lo (lda >= Kc).  B: [Nc_pad][Kc] bf16 hi/lo.
// prods: 3 = AhBh+AhBl+AlBh ; 2 = AhBh+AhBl (A single precision).
// Output: fp32 C, or bf16 hi/lo split if Chi != nullptr. Epilogue guards gc < Nc.
__global__ __launch_bounds__(256) void gemm_mfma_k(
    const u16* __restrict__ Ah, const u16* __restrict__ Al,
    const u16* __restrict__ Bh, const u16* __restrict__ Bl,
    float* __restrict__ C, u16* __restrict__ Chi, u16* __restrict__ Clo,
    int M, int Kc, int Nc, int lda,
    long sA, long sB, long sC, const float* __restrict__ bias, int act, int prods)
{
    __shared__ u16 sAh[128*32], sAl[128*32], sBh[128*32], sBl[128*32];  // 32 KB
    const int bz = blockIdx.z;
    const u16* gAh = Ah + (long)bz*sA;
    const u16* gAl = Al + (long)bz*sA;
    const u16* gBh = Bh + (long)bz*sB;
    const u16* gBl = Bl + (long)bz*sB;
    const int tid = threadIdx.x;
    const int wave = tid >> 6, lane = tid & 63;
    const int quad = lane >> 4, r16 = lane & 15;
    const int m0 = blockIdx.y*128, n0 = blockIdx.x*128;
    const int wm = (wave>>1)*64, wn = (wave&1)*64;

    f32x4 acc[4][4];
    #pragma unroll
    for (int i=0;i<4;i++)
        #pragma unroll
        for (int j=0;j<4;j++) acc[i][j] = (f32x4){0.f,0.f,0.f,0.f};

    for (int k0 = 0; k0 < Kc; k0 += 32){
        __syncthreads();
        #pragma unroll
        for (int half=0; half<2; ++half){
            int c = half*256 + tid;
            int row = c >> 2, kg = (c & 3)*8;
            long ga = (long)(m0+row)*lda + k0 + kg;
            long gb = (long)(n0+row)*Kc + k0 + kg;
            gload16(gAh+ga, &sAh[c*8]);
            if (prods == 3) gload16(gAl+ga, &sAl[c*8]);
            gload16(gBh+gb, &sBh[c*8]);
            gload16(gBl+gb, &sBl[c*8]);
        }
        __syncthreads();
        bf16x8 afh[4], afl[4], bfh[4], bfl[4];
        #pragma unroll
        for (int i=0;i<4;i++){
            afh[i] = *(const bf16x8*)&sAh[(wm+i*16+r16)*32 + quad*8];
            bfh[i] = *(const bf16x8*)&sBh[(wn+i*16+r16)*32 + quad*8];
            bfl[i] = *(const bf16x8*)&sBl[(wn+i*16+r16)*32 + quad*8];
        }
        if (prods == 3){
            #pragma unroll
            for (int i=0;i<4;i++) afl[i] = *(const bf16x8*)&sAl[(wm+i*16+r16)*32 + quad*8];
        }
        #pragma unroll
        for (int i=0;i<4;i++)
            #pragma unroll
            for (int j=0;j<4;j++){
                acc[i][j] = __builtin_amdgcn_mfma_f32_16x16x32_bf16(afh[i], bfh[j], acc[i][j], 0,0,0);
                acc[i][j] = __builtin_amdgcn_mfma_f32_16x16x32_bf16(afh[i], bfl[j], acc[i][j], 0,0,0);
                if (prods == 3)
                    acc[i][j] = __builtin_amdgcn_mfma_f32_16x16x32_bf16(afl[i], bfh[j], acc[i][j], 0,0,0);
            }
    }
    // epilogue: C/D layout col=lane&15, row=quad*4+reg
    #pragma unroll
    for (int i=0;i<4;i++){
        #pragma unroll
        for (int j=0;j<4;j++){
            int gc = n0 + wn + j*16 + r16;
            if (gc >= Nc) continue;
            float bv = bias ? bias[gc] : 0.f;
            #pragma unroll
            for (int r=0;r<4;r++){
                long gr = m0 + wm + i*16 + quad*4 + r;
                float v = acc[i][j][r] + bv;
                if (act) v = gelu_tanh(v);
                long o = (long)bz*sC + gr*Nc + gc;
                if (Chi){
                    u16 hh = f2bf(v);
                    Chi[o] = hh;
                    Clo[o] = f2bf(v - bf2f(hh));
                } else {
                    C[o] = v;
                }
            }
        }
    }
}

// ---------------------------------------------------------------- LayerNorm (rows of 512)
__global__ __launch_bounds__(256) void ln_k(
    const float* __restrict__ x, const float* __restrict__ g,
    const float* __restrict__ be, float* __restrict__ y)
{
    __shared__ float sh[8];
    const int r = blockIdx.x, tid = threadIdx.x;
    const float* xr = x + (long)r*KK;
    float2 v = *(const float2*)(xr + tid*2);
    float s = v.x+v.y, s2 = v.x*v.x+v.y*v.y;
    #pragma unroll
    for (int o=32;o>0;o>>=1){ s += __shfl_down(s,o); s2 += __shfl_down(s2,o); }
    if ((tid&63)==0){ sh[tid>>6]=s; sh[4+(tid>>6)]=s2; }
    __syncthreads();
    s  = sh[0]+sh[1]+sh[2]+sh[3];
    s2 = sh[4]+sh[5]+sh[6]+sh[7];
    const float mean = s*(1.f/KK);
    const float var  = s2*(1.f/KK) - mean*mean;
    const float rs = rsqrtf(var + 1e-5f);
    float2 gg = *(const float2*)(g + tid*2);
    float2 bb = *(const float2*)(be + tid*2);
    float2 o;
    o.x = (v.x-mean)*rs*gg.x + bb.x;
    o.y = (v.y-mean)*rs*gg.y + bb.y;
    *(float2*)(y + (long)r*KK + tid*2) = o;
}

// ---------------------------------------------------------------- small elementwise kernels
__global__ void combine_k(const float* __restrict__ t, const float* __restrict__ phi,
                          float* __restrict__ a, float sign){
    int idx = blockIdx.x*256 + threadIdx.x;
    if (idx >= BN*KK/4) return;
    int r = idx >> 7;
    int c4 = (idx & 127) << 2;
    const float* ph = phi + r*3;
    float p0 = sign*ph[0], p1 = sign*ph[1], p2 = sign*ph[2];
    const float* tr = t + (long)r*(3*KK);
    float4 t0 = *(const float4*)(tr + c4);
    float4 t1 = *(const float4*)(tr + KK + c4);
    float4 t2 = *(const float4*)(tr + 2*KK + c4);
    float4 o;
    o.x = p0*t0.x + p1*t1.x + p2*t2.x;
    o.y = p0*t0.y + p1*t1.y + p2*t2.y;
    o.z = p0*t0.z + p1*t1.z + p2*t2.z;
    o.w = p0*t0.w + p1*t1.w + p2*t2.w;
    *(float4*)(a + (long)r*KK + c4) = o;
}
__global__ void tfinal_k(const float* __restrict__ x, const float* __restrict__ a1,
                         const float* __restrict__ a2, const float* __restrict__ res,
                         float* __restrict__ out){
    int i = blockIdx.x*256 + threadIdx.x;
    if (i >= BN*KK/4) return;
    float4 xv = ((const float4*)x)[i];
    float4 v1 = ((const float4*)a1)[i];
    float4 v2 = ((const float4*)a2)[i];
    float4 o;
    o.x = xv.x + v1.x + 0.5f*v2.x;
    o.y = xv.y + v1.y + 0.5f*v2.y;
    o.z = xv.z + v1.z + 0.5f*v2.z;
    o.w = xv.w + v1.w + 0.5f*v2.w;
    if (res){ float4 rv = ((const float4*)res)[i]; o.x+=rv.x; o.y+=rv.y; o.z+=rv.z; o.w+=rv.w; }
    ((float4*)out)[i] = o;
}
__global__ void copy_k(const float* __restrict__ s, float* __restrict__ d, int n4){
    int i = blockIdx.x*256 + threadIdx.x;
    if (i < n4) ((float4*)d)[i] = ((const float4*)s)[i];
}
__global__ void final_k(const float* __restrict__ a, const float* __restrict__ b,
                        const float* __restrict__ c, float* __restrict__ out){
    int i = blockIdx.x*256 + threadIdx.x;
    if (i >= BN*KK/4) return;
    float4 av = ((const float4*)a)[i], bv = ((const float4*)b)[i], cv = ((const float4*)c)[i];
    float4 o;
    o.x = av.x + bv.x - cv.x; o.y = av.y + bv.y - cv.y;
    o.z = av.z + bv.z - cv.z; o.w = av.w + bv.w - cv.w;
    ((float4*)out)[i] = o;
}
__global__ void ffn_update_k(float* __restrict__ h, const float* __restrict__ drive,
                             const float* __restrict__ bmh, const float* __restrict__ mup,
                             const float* __restrict__ lr){
    int i = blockIdx.x*256 + threadIdx.x;
    if (i >= BN*KK/4) return;
    const float lrv = *lr;
    float4 hv = ((float4*)h)[i];
    float4 dv = ((const float4*)drive)[i];
    float4 bv = ((const float4*)bmh)[i];
    float4 pv = ((const float4*)mup)[i];
    float4 o;
    o.x = hv.x + lrv*(dv.x - (1e-3f*(hv.x-pv.x) + 1.0f*(hv.x-bv.x)));
    o.y = hv.y + lrv*(dv.y - (1e-3f*(hv.y-pv.y) + 1.0f*(hv.y-bv.y)));
    o.z = hv.z + lrv*(dv.z - (1e-3f*(hv.z-pv.z) + 1.0f*(hv.z-bv.z)));
    o.w = hv.w + lrv*(dv.w - (1e-3f*(hv.w-pv.w) + 1.0f*(hv.w-bv.w)));
    ((float4*)h)[i] = o;
}

// ---------------------------------------------------------------- attention prep
// block per (b,n), 512 thr = 8 waves (one per head). Builds CF/KS (H,B,N,128) split bf16
// CF = [inv, -2*q*inv], KS = [skk, k]; dvec[(h*BB+b)*NN+n] = sum log(sk).
__global__ __launch_bounds__(512) void prep2_k(
    const float* __restrict__ qm, const float* __restrict__ km,
    const float* __restrict__ sqm, const float* __restrict__ skm,
    u16* __restrict__ CFh, u16* __restrict__ CFl,
    u16* __restrict__ KSh, u16* __restrict__ KSl, float* __restrict__ dvec)
{
    const int bn = blockIdx.x;
    const int b = bn / NN, n = bn % NN;
    const int h = threadIdx.x >> 6, d = threadIdx.x & 63;
    const long idx = (long)bn*KK + h*DHh + d;
    float q  = qm[idx], k = km[idx];
    float sq = sqm[idx] + 1e-8f;
    float sk = skm[idx] + 1e-8f;
    float inv = 1.f/sq;
    float nqi = -2.f*q*inv;
    float skk = sk + k*k;
    const size_t base = ((size_t)(h*BB + b)*NN + n)*128;
    u16 hh;
    hh = f2bf(inv); CFh[base+d]    = hh; CFl[base+d]    = f2bf(inv - bf2f(hh));
    hh = f2bf(nqi); CFh[base+64+d] = hh; CFl[base+64+d] = f2bf(nqi - bf2f(hh));
    hh = f2bf(skk); KSh[base+d]    = hh; KSl[base+d]    = f2bf(skk - bf2f(hh));
    hh = f2bf(k);   KSh[base+64+d] = hh; KSl[base+64+d] = f2bf(k   - bf2f(hh));
    float dv = __logf(sk);
    #pragma unroll
    for (int o=32;o>0;o>>=1) dv += __shfl_down(dv,o);
    if (d==0) dvec[((size_t)h*BB + b)*NN + n] = dv;
}

// ---------------------------------------------------------------- V transpose+split: (B,N,512) -> (H,B,128,NN), rows 64..127 zero
__global__ __launch_bounds__(256) void vtsplit_k(
    const float* __restrict__ vm, u16* __restrict__ VTh, u16* __restrict__ VTl)
{
    __shared__ float t[64][65];
    const int n0 = blockIdx.x * 64;
    const int h = blockIdx.y, b = blockIdx.z;
    const int tid = threadIdx.x;
    const int c4 = (tid & 15) * 4;
    const int r0 = tid >> 4;
    for (int rr = r0; rr < 64; rr += 16){
        float4 v = *(const float4*)(vm + (size_t)(b*NN + n0 + rr)*KK + h*DHh + c4);
        t[c4+0][rr] = v.x; t[c4+1][rr] = v.y; t[c4+2][rr] = v.z; t[c4+3][rr] = v.w;
    }
    __syncthreads();
    for (int dd = r0; dd < 64; dd += 16){
        size_t base = ((size_t)(h*BB + b)*128 + dd)*NN + n0 + c4;
        #pragma unroll
        for (int q=0;q<4;q++){
            float v = t[dd][c4+q];
            u16 hh = f2bf(v);
            VTh[base+q] = hh;
            VTl[base+q] = f2bf(v - bf2f(hh));
        }
    }
    for (int dd = 64 + r0; dd < 128; dd += 16){
        size_t base = ((size_t)(h*BB + b)*128 + dd)*NN + n0 + c4;
        *(unsigned long long*)&VTh[base] = 0ull;
        *(unsigned long long*)&VTl[base] = 0ull;
    }
}

// ---------------------------------------------------------------- softmax over a head-group of 4
// block per (b,i): for hg in 0..3 read dot row from S (z=hg*BB+b), softmax(-0.5*dot+0.5*d_j),
// write beta as bf16 IN PLACE over S row (u16, first half), accumulate beta_m.
__global__ __launch_bounds__(256) void softmax2_k(
    float* __restrict__ S, const float* __restrict__ dvec,
    float* __restrict__ betam, int g)
{
    __shared__ float s_sc[NN];
    __shared__ float s_bm[NN];
    __shared__ float s_red[4];
    const int tid = threadIdx.x;
    const int b = blockIdx.x / NN, i = blockIdx.x % NN;
    const int L = i + 1;
    for (int j=tid;j<NN;j+=256) s_bm[j]=0.f;
    for (int hg=0; hg<4; ++hg){
        const int z = hg*BB + b;
        float* row = S + ((long)z*NN + i)*NN;
        const float* dp = dvec + ((size_t)(g*4+hg)*BB + b)*NN;
        float lm = -3.0e38f;
        for (int j=tid;j<L;j+=256){
            float sc = -0.5f*row[j] + 0.5f*dp[j];
            s_sc[j] = sc;
            lm = fmaxf(lm, sc);
        }
        #pragma unroll
        for (int o=32;o>0;o>>=1) lm = fmaxf(lm, __shfl_xor(lm, o));
        __syncthreads();
        if ((tid&63)==0) s_red[tid>>6] = lm;
        __syncthreads();
        const float mx = fmaxf(fmaxf(s_red[0],s_red[1]), fmaxf(s_red[2],s_red[3]));
        float ps = 0.f;
        for (int j=tid;j<L;j+=256){
            float e = __expf(s_sc[j]-mx);
            s_sc[j] = e;
            ps += e;
        }
        #pragma unroll
        for (int o=32;o>0;o>>=1) ps += __shfl_xor(ps, o);
        __syncthreads();
        if ((tid&63)==0) s_red[tid>>6] = ps;
        __syncthreads();
        const float isum = 1.f/(s_red[0]+s_red[1]+s_red[2]+s_red[3]);
        u16* brow = (u16*)row;   // in-place: full row already consumed into s_sc
        for (int j=tid;j<NN;j+=256){
            if (j < L){
                float w = s_sc[j]*isum;
                brow[j] = f2bf(w);
                s_bm[j] += 0.125f*w;
            } else {
                brow[j] = 0;
            }
        }
        __syncthreads();
    }
    const long bmrow = ((long)b*NN + i)*NN;
    if (g == 0){
        for (int j=tid;j<NN;j+=256) betam[bmrow+j] = s_bm[j];
    } else {
        for (int j=tid;j<NN;j+=256) betam[bmrow+j] += s_bm[j];
    }
}

// ---------------------------------------------------------------- PV output gather: (z,i,64) -> Xb(b,i,512)
__global__ void pvcomb_k(const float* __restrict__ pv, float* __restrict__ x, int g){
    int idx = blockIdx.x*256 + threadIdx.x;
    if (idx >= 16*NN*64) return;
    int d = idx & 63;
    int rest = idx >> 6;
    int i = rest % NN;
    int z = rest / NN;
    int b = z & 3, hg = z >> 2;
    x[((long)b*NN+i)*KK + (g*4+hg)*64 + d] = pv[idx];
}

// ---------------------------------------------------------------- launch
extern "C" void kernel_launch(void* const* d_in, const int* in_sizes, int n_in,
                              void* d_out, int out_size, void* d_ws, size_t ws_size,
                              hipStream_t stream) {
    const float* mu_q    = (const float*)d_in[0];
    const float* sigma_q = (const float*)d_in[1];
    const float* phi     = (const float*)d_in[2];
    const float* gen     = (const float*)d_in[3];
    const float* mu_prior= (const float*)d_in[5];
    const float* Wq = (const float*)d_in[6];
    const float* Wk = (const float*)d_in[7];
    const float* Wv = (const float*)d_in[8];
    const float* Wo = (const float*)d_in[9];
    const float* g1 = (const float*)d_in[10];
    const float* be1= (const float*)d_in[11];
    const float* g2 = (const float*)d_in[12];
    const float* be2= (const float*)d_in[13];
    const float* W1 = (const float*)d_in[14];
    const float* bh1= (const float*)d_in[15];
    const float* W2 = (const float*)d_in[16];
    const float* bh2= (const float*)d_in[17];
    const float* lr = (const float*)d_in[18];
    float* out = (float*)d_out;

    float* w = (float*)d_ws;
    size_t off = 0;
    auto alloc = [&](size_t n){ float* p = w + off; off += (n+3)&~(size_t)3; return p; };
    auto ualloc = [&](size_t n){ return (u16*)alloc((n+1)/2); };

    // fp32 buffers
    float* Xb   = alloc((size_t)BN*KK);        // mu_n -> mu_g -> attn_out
    float* A1b  = alloc((size_t)BN*KK);
    float* A2b  = alloc((size_t)BN*KK);        // also PVout (16*NN*64 = 1.05M <= 2M)
    float* Qb   = alloc((size_t)BN*KK);
    float* Kb   = alloc((size_t)BN*KK);
    float* Vb   = alloc((size_t)BN*KK);
    float* SQb  = alloc((size_t)BN*KK);
    float* SKb  = alloc((size_t)BN*KK);
    // shared region: Tb (BN*3*KK=6M) / S (16*NN*NN=16.78M) / ZH+ZL (16.78M u16 = 8.39M fl)
    float* REG  = alloc((size_t)16*NN*NN);
    float* Tb   = REG;
    float* Sbuf = REG;
    u16*  ZH    = (u16*)REG;
    u16*  ZL    = ZH + (size_t)BN*HIDd;
    float* Db_  = alloc((size_t)HH*BB*NN);
    float* BMb  = alloc((size_t)BB*NN*NN);
    // AH/AL scratch, aliased as CF/KS during attention
    u16* AH  = ualloc((size_t)BN*HIDd); u16* AL  = ualloc((size_t)BN*HIDd);
    u16* CFh = AH;
    u16* CFl = AH + (size_t)HH*BB*NN*128;      // 4.19M u16 each; 4 arrays = 16.78M = AH+AL
    u16* KSh = AL;
    u16* KSl = AL + (size_t)HH*BB*NN*128;
    u16* VTh = ualloc((size_t)HH*BB*128*NN);
    u16* VTl = ualloc((size_t)HH*BB*128*NN);
    // weights (persistent)
    u16* GTh = ualloc((size_t)3*KK*KK); u16* GTl = ualloc((size_t)3*KK*KK);
    u16* WqTh= ualloc((size_t)KK*KK);   u16* WqTl= ualloc((size_t)KK*KK);
    u16* WkTh= ualloc((size_t)KK*KK);   u16* WkTl= ualloc((size_t)KK*KK);
    u16* WvTh= ualloc((size_t)KK*KK);   u16* WvTl= ualloc((size_t)KK*KK);
    u16* WoTh= ualloc((size_t)KK*KK);   u16* WoTl= ualloc((size_t)KK*KK);
    u16* Wq2h= ualloc((size_t)KK*KK);   u16* Wq2l= ualloc((size_t)KK*KK);
    u16* Wk2h= ualloc((size_t)KK*KK);   u16* Wk2l= ualloc((size_t)KK*KK);
    u16* W1Th= ualloc((size_t)KK*HIDd); u16* W1Tl= ualloc((size_t)KK*HIDd);
    u16* W2Th= ualloc((size_t)KK*HIDd); u16* W2Tl= ualloc((size_t)KK*HIDd);
    u16* BMh = ualloc((size_t)BB*NN*NN);u16* BMl = ualloc((size_t)BB*NN*NN);
    u16* HTh = ualloc((size_t)BB*KK*NN);u16* HTl = ualloc((size_t)BB*KK*NN);
    float* PVout = A2b;

    auto gemm = [&](const u16* ah, const u16* al, const u16* bh, const u16* bl,
                    float* C, u16* chi, u16* clo, int M, int Kc, int Nc, int lda,
                    long sA, long sB, long sC, const float* bias, int act,
                    int prods, int batch){
        dim3 g((Nc+127)/128, M/128, batch);
        gemm_mfma_k<<<g, 256, 0, stream>>>(ah, al, bh, bl, C, chi, clo,
                                           M, Kc, Nc, lda, sA, sB, sC, bias, act, prods);
    };
    auto splitA = [&](const float* src, long n){
        split_k<<<(int)((n+255)/256), 256, 0, stream>>>(src, AH, AL, n);
    };

    // ---- weight prep (once) ----
    split_k<<<(3*KK*KK+255)/256, 256, 0, stream>>>(gen, GTh, GTl, (long)3*KK*KK);
    {
        dim3 gq(KK/32, KK/32, 1);
        split_t_k<<<gq, 256, 0, stream>>>(Wq, WqTh, WqTl, KK, KK, 0L, 0L, 0);
        split_t_k<<<gq, 256, 0, stream>>>(Wk, WkTh, WkTl, KK, KK, 0L, 0L, 0);
        split_t_k<<<gq, 256, 0, stream>>>(Wv, WvTh, WvTl, KK, KK, 0L, 0L, 0);
        split_t_k<<<gq, 256, 0, stream>>>(Wo, WoTh, WoTl, KK, KK, 0L, 0L, 0);
        split_t_k<<<gq, 256, 0, stream>>>(Wq, Wq2h, Wq2l, KK, KK, 0L, 0L, 1);
        split_t_k<<<gq, 256, 0, stream>>>(Wk, Wk2h, Wk2l, KK, KK, 0L, 0L, 1);
        dim3 g1g(HIDd/32, KK/32, 1);
        split_t_k<<<g1g, 256, 0, stream>>>(W1, W1Th, W1Tl, KK, HIDd, 0L, 0L, 0);
        dim3 g2g(KK/32, HIDd/32, 1);
        split_t_k<<<g2g, 256, 0, stream>>>(W2, W2Th, W2Tl, HIDd, KK, 0L, 0L, 0);
    }

    // ---- phase A: LN1 + forward transport ----
    ln_k<<<BN, 256, 0, stream>>>(mu_q, g1, be1, Xb);
    splitA(Xb, (long)BN*KK);
    gemm(AH, AL, GTh, GTl, Tb, 0,0, BN, KK, 3*KK, KK, 0,0,0, nullptr, 0, 3, 1);
    combine_k<<<BN*KK/4/256, 256, 0, stream>>>(Tb, phi, A1b, 1.f);
    splitA(A1b, (long)BN*KK);
    gemm(AH, AL, GTh, GTl, Tb, 0,0, BN, KK, 3*KK, KK, 0,0,0, nullptr, 0, 3, 1);
    combine_k<<<BN*KK/4/256, 256, 0, stream>>>(Tb, phi, A2b, 1.f);
    tfinal_k<<<BN*KK/4/256, 256, 0, stream>>>(Xb, A1b, A2b, nullptr, Xb);   // mu_g

    // ---- phase B: projections + attention prep ----
    splitA(Xb, (long)BN*KK);
    gemm(AH, AL, WqTh, WqTl, Qb, 0,0, BN, KK, KK, KK, 0,0,0, nullptr, 0, 3, 1);
    gemm(AH, AL, WkTh, WkTl, Kb, 0,0, BN, KK, KK, KK, 0,0,0, nullptr, 0, 3, 1);
    gemm(AH, AL, WvTh, WvTl, Vb, 0,0, BN, KK, KK, KK, 0,0,0, nullptr, 0, 3, 1);
    splitA(sigma_q, (long)BN*KK);
    gemm(AH, AL, Wq2h, Wq2l, SQb, 0,0, BN, KK, KK, KK, 0,0,0, nullptr, 0, 3, 1);
    gemm(AH, AL, Wk2h, Wk2l, SKb, 0,0, BN, KK, KK, KK, 0,0,0, nullptr, 0, 3, 1);
    // CF/KS overwrite the AH/AL region (safe: prior gemms complete first)
    prep2_k<<<BN, 512, 0, stream>>>(Qb, Kb, SQb, SKb, CFh, CFl, KSh, KSl, Db_);
    {
        dim3 tg(NN/64, HH, BB);
        vtsplit_k<<<tg, 256, 0, stream>>>(Vb, VTh, VTl);
    }

    // ---- phase C: attention, two head-groups of 4 ----
    for (int g = 0; g < 2; ++g){
        size_t cfo = (size_t)g*4*BB*NN*128;
        // S = CF @ KS^T  (z = hg*BB+b, 16 batches)
        gemm(CFh+cfo, CFl+cfo, KSh+cfo, KSl+cfo, Sbuf, 0,0,
             NN, 128, NN, 128, (long)NN*128, (long)NN*128, (long)NN*NN,
             nullptr, 0, 3, 16);
        softmax2_k<<<BB*NN, 256, 0, stream>>>(Sbuf, Db_, BMb, g);
        // PV: beta(bf16 in-place over S, lda=2*NN) @ V^T  -> PVout
        size_t vto = (size_t)g*4*BB*128*NN;
        gemm((const u16*)Sbuf, (const u16*)Sbuf, VTh+vto, VTl+vto, PVout, 0,0,
             NN, NN, 64, 2*NN, (long)NN*NN*2, (long)128*NN, (long)NN*64,
             nullptr, 0, 2, 16);
        pvcomb_k<<<(16*NN*64)/256, 256, 0, stream>>>(PVout, Xb, g);
    }

    // ---- phase D: output proj + back transport + residual + LN2 ----
    splitA(Xb, (long)BN*KK);
    gemm(AH, AL, WoTh, WoTl, A1b, 0,0, BN, KK, KK, KK, 0,0,0, nullptr, 0, 3, 1);
    splitA(A1b, (long)BN*KK);
    gemm(AH, AL, GTh, GTl, Tb, 0,0, BN, KK, 3*KK, KK, 0,0,0, nullptr, 0, 3, 1);
    combine_k<<<BN*KK/4/256, 256, 0, stream>>>(Tb, phi, A2b, -1.f);
    splitA(A2b, (long)BN*KK);
    gemm(AH, AL, GTh, GTl, Tb, 0,0, BN, KK, 3*KK, KK, 0,0,0, nullptr, 0, 3, 1);
    combine_k<<<BN*KK/4/256, 256, 0, stream>>>(Tb, phi, Qb, -1.f);
    tfinal_k<<<BN*KK/4/256, 256, 0, stream>>>(A1b, A2b, Qb, mu_q, Kb);      // mu_res
    ln_k<<<BN, 256, 0, stream>>>(Kb, g2, be2, Vb);                          // mu_n2
    copy_k<<<BN*KK/4/256, 256, 0, stream>>>(Vb, SQb, BN*KK/4);              // h = mu_n2

    // beta_m split (constant across iterations)
    split_k<<<(int)(((long)BB*NN*NN+255)/256), 256, 0, stream>>>(BMb, BMh, BMl, (long)BB*NN*NN);

    // ---- phase E: 2 VFE iterations ----
    for (int it=0; it<2; ++it){
        splitA(SQb, (long)BN*KK);                                            // h
        gemm(AH, AL, W1Th, W1Tl, 0, ZH, ZL, BN, KK, HIDd, KK, 0,0,0, bh1, 1, 3, 1); // gelu split out
        gemm(ZH, ZL, W2Th, W2Tl, SKb, 0,0, BN, HIDd, KK, HIDd, 0,0,0, bh2, 0, 3, 1); // drive
        {
            dim3 tg(KK/32, NN/32, BB);
            split_t_k<<<tg, 256, 0, stream>>>(SQb, HTh, HTl, NN, KK,
                                              (long)NN*KK, (long)KK*NN, 0);
        }
        gemm(BMh, BMl, HTh, HTl, A1b, 0,0, NN, NN, KK, NN,
             (long)NN*NN, (long)KK*NN, (long)NN*KK, nullptr, 0, 3, BB);      // bmh
        ffn_update_k<<<BN*KK/4/256, 256, 0, stream>>>(SQb, SKb, A1b, mu_prior, lr);
    }

    // ---- phase F: outputs ----
    final_k<<<BN*KK/4/256, 256, 0, stream>>>(Kb, SQb, Vb, out);
    copy_k<<<BN*KK/4/256, 256, 0, stream>>>(sigma_q, out + (size_t)BN*KK, BN*KK/4);
    copy_k<<<(BN*3/4+255)/256, 256, 0, stream>>>(phi, out + 2*(size_t)BN*KK, BN*3/4);

    (void)in_sizes; (void)n_in; (void)out_size; (void)ws_size;
}

// Round 5
// 1054.858 us; speedup vs baseline: 4.3147x; 1.2095x over previous
//
#include <hip/hip_runtime.h>
#include <math.h>

#define BB 4
#define NN 1024
#define KK 512
#define HH 8
#define DHh 64
#define HIDd 2048
#define BN (BB*NN)

typedef unsigned short u16;
typedef __attribute__((ext_vector_type(8))) short bf16x8;
typedef __attribute__((ext_vector_type(4))) float f32x4;

// ---------------------------------------------------------------- helpers
__device__ __forceinline__ float gelu_tanh(float x){
    float x3 = x*x*x;
    float t = tanhf(0.7978845608028654f*(x + 0.044715f*x3));
    return 0.5f*x*(1.0f+t);
}
__device__ __forceinline__ u16 f2bf(float x){
    unsigned int u = __float_as_uint(x);
    unsigned int r = (u + 0x7fffu + ((u>>16)&1u)) >> 16;
    return (u16)r;
}
__device__ __forceinline__ float bf2f(u16 b){
    return __uint_as_float(((unsigned int)b)<<16);
}
__device__ __forceinline__ void gload16(const void* g, void* l){
    __builtin_amdgcn_global_load_lds((__attribute__((address_space(1))) void*)g,
                                     (__attribute__((address_space(3))) void*)l, 16, 0, 0);
}
__device__ __forceinline__ void wsplit(u16* hi, u16* lo, size_t o, float v){
    u16 h = f2bf(v);
    hi[o] = h;
    lo[o] = f2bf(v - bf2f(h));
}

// ---------------------------------------------------------------- split conversions
__global__ __launch_bounds__(256) void split_k(const float* __restrict__ src,
                                               u16* __restrict__ hi, u16* __restrict__ lo, long n){
    long i = (long)blockIdx.x*256 + threadIdx.x;
    if (i >= n) return;
    wsplit(hi, lo, i, src[i]);
}

// src [Kc][Nc] (row-major, +batch stride sS) -> dst [Nc][Kc] hi/lo bf16 (+batch sD). square opt.
__global__ __launch_bounds__(256) void split_t_k(
    const float* __restrict__ src, u16* __restrict__ hi, u16* __restrict__ lo,
    int Kc, int Nc, long sS, long sD, int square)
{
    __shared__ float t[32][33];
    const int n0 = blockIdx.x*32, k0 = blockIdx.y*32, bz = blockIdx.z;
    const float* S = src + (long)bz*sS;
    const int tx = threadIdx.x & 31, ty = threadIdx.x >> 5;
    for (int r = ty; r < 32; r += 8){
        float v = S[(long)(k0+r)*Nc + n0+tx];
        if (square) v *= v;
        t[r][tx] = v;
    }
    __syncthreads();
    for (int r = ty; r < 32; r += 8){
        float v = t[tx][r];
        long o = (long)bz*sD + (long)(n0+r)*Kc + k0 + tx;
        wsplit(hi, lo, o, v);
    }
}

// ---------------------------------------------------------------- MFMA GEMM (split bf16, ~fp32 acc)
// C = A*B^T, 3 products AhBh+AhBl+AlBh.  A: [M][lda] hi/lo.  B: [Nc_pad][Kc] hi/lo.
// Writes fp32 C (if C) and/or split bf16 (if Chi). cskip: 1 = skip blocks n0>m0+127 (causal S),
// 2 = trim K to m0+128 (lower-triangular A).
__global__ __launch_bounds__(256) void gemm_mfma_k(
    const u16* __restrict__ Ah, const u16* __restrict__ Al,
    const u16* __restrict__ Bh, const u16* __restrict__ Bl,
    float* __restrict__ C, u16* __restrict__ Chi, u16* __restrict__ Clo,
    int M, int Kc, int Nc, int lda,
    long sA, long sB, long sC, const float* __restrict__ bias, int act, int cskip)
{
    __shared__ u16 sAh[128*32], sAl[128*32], sBh[128*32], sBl[128*32];  // 32 KB
    const int m0 = blockIdx.y*128, n0 = blockIdx.x*128;
    if (cskip == 1 && n0 > m0 + 127) return;
    const int bz = blockIdx.z;
    const u16* gAh = Ah + (long)bz*sA;
    const u16* gAl = Al + (long)bz*sA;
    const u16* gBh = Bh + (long)bz*sB;
    const u16* gBl = Bl + (long)bz*sB;
    const int tid = threadIdx.x;
    const int wave = tid >> 6, lane = tid & 63;
    const int quad = lane >> 4, r16 = lane & 15;
    const int wm = (wave>>1)*64, wn = (wave&1)*64;
    const int kend = (cskip == 2) ? min(Kc, m0+128) : Kc;

    f32x4 acc[4][4];
    #pragma unroll
    for (int i=0;i<4;i++)
        #pragma unroll
        for (int j=0;j<4;j++) acc[i][j] = (f32x4){0.f,0.f,0.f,0.f};

    for (int k0 = 0; k0 < kend; k0 += 32){
        __syncthreads();
        #pragma unroll
        for (int half=0; half<2; ++half){
            int c = half*256 + tid;
            int row = c >> 2, kg = (c & 3)*8;
            long ga = (long)(m0+row)*lda + k0 + kg;
            long gb = (long)(n0+row)*Kc + k0 + kg;
            gload16(gAh+ga, &sAh[c*8]);
            gload16(gAl+ga, &sAl[c*8]);
            gload16(gBh+gb, &sBh[c*8]);
            gload16(gBl+gb, &sBl[c*8]);
        }
        __syncthreads();
        bf16x8 afh[4], afl[4], bfh[4], bfl[4];
        #pragma unroll
        for (int i=0;i<4;i++){
            afh[i] = *(const bf16x8*)&sAh[(wm+i*16+r16)*32 + quad*8];
            afl[i] = *(const bf16x8*)&sAl[(wm+i*16+r16)*32 + quad*8];
            bfh[i] = *(const bf16x8*)&sBh[(wn+i*16+r16)*32 + quad*8];
            bfl[i] = *(const bf16x8*)&sBl[(wn+i*16+r16)*32 + quad*8];
        }
        #pragma unroll
        for (int i=0;i<4;i++)
            #pragma unroll
            for (int j=0;j<4;j++){
                acc[i][j] = __builtin_amdgcn_mfma_f32_16x16x32_bf16(afh[i], bfh[j], acc[i][j], 0,0,0);
                acc[i][j] = __builtin_amdgcn_mfma_f32_16x16x32_bf16(afh[i], bfl[j], acc[i][j], 0,0,0);
                acc[i][j] = __builtin_amdgcn_mfma_f32_16x16x32_bf16(afl[i], bfh[j], acc[i][j], 0,0,0);
            }
    }
    // epilogue: C/D layout col=lane&15, row=quad*4+reg
    #pragma unroll
    for (int i=0;i<4;i++){
        #pragma unroll
        for (int j=0;j<4;j++){
            int gc = n0 + wn + j*16 + r16;
            if (gc >= Nc) continue;
            float bv = bias ? bias[gc] : 0.f;
            #pragma unroll
            for (int r=0;r<4;r++){
                long gr = m0 + wm + i*16 + quad*4 + r;
                float v = acc[i][j][r] + bv;
                if (act) v = gelu_tanh(v);
                long o = (long)bz*sC + gr*Nc + gc;
                if (C) C[o] = v;
                if (Chi) wsplit(Chi, Clo, o, v);
            }
        }
    }
}

// ---------------------------------------------------------------- LayerNorm (rows of 512), optional split out
__global__ __launch_bounds__(256) void ln_k(
    const float* __restrict__ x, const float* __restrict__ g,
    const float* __restrict__ be, float* __restrict__ y,
    u16* __restrict__ yh, u16* __restrict__ yl)
{
    __shared__ float sh[8];
    const int r = blockIdx.x, tid = threadIdx.x;
    const float* xr = x + (long)r*KK;
    float2 v = *(const float2*)(xr + tid*2);
    float s = v.x+v.y, s2 = v.x*v.x+v.y*v.y;
    #pragma unroll
    for (int o=32;o>0;o>>=1){ s += __shfl_down(s,o); s2 += __shfl_down(s2,o); }
    if ((tid&63)==0){ sh[tid>>6]=s; sh[4+(tid>>6)]=s2; }
    __syncthreads();
    s  = sh[0]+sh[1]+sh[2]+sh[3];
    s2 = sh[4]+sh[5]+sh[6]+sh[7];
    const float mean = s*(1.f/KK);
    const float var  = s2*(1.f/KK) - mean*mean;
    const float rs = rsqrtf(var + 1e-5f);
    float2 gg = *(const float2*)(g + tid*2);
    float2 bb = *(const float2*)(be + tid*2);
    float ox = (v.x-mean)*rs*gg.x + bb.x;
    float oy = (v.y-mean)*rs*gg.y + bb.y;
    long o = (long)r*KK + tid*2;
    *(float2*)(y + o) = make_float2(ox, oy);
    if (yh){ wsplit(yh, yl, o, ox); wsplit(yh, yl, o+1, oy); }
}

// ---------------------------------------------------------------- elementwise kernels
__global__ void combine_k(const float* __restrict__ t, const float* __restrict__ phi,
                          float* __restrict__ a, u16* __restrict__ ah, u16* __restrict__ al,
                          float sign){
    int idx = blockIdx.x*256 + threadIdx.x;
    if (idx >= BN*KK/4) return;
    int r = idx >> 7;
    int c4 = (idx & 127) << 2;
    const float* ph = phi + r*3;
    float p0 = sign*ph[0], p1 = sign*ph[1], p2 = sign*ph[2];
    const float* tr = t + (long)r*(3*KK);
    float4 t0 = *(const float4*)(tr + c4);
    float4 t1 = *(const float4*)(tr + KK + c4);
    float4 t2 = *(const float4*)(tr + 2*KK + c4);
    float4 o;
    o.x = p0*t0.x + p1*t1.x + p2*t2.x;
    o.y = p0*t0.y + p1*t1.y + p2*t2.y;
    o.z = p0*t0.z + p1*t1.z + p2*t2.z;
    o.w = p0*t0.w + p1*t1.w + p2*t2.w;
    long ob = (long)r*KK + c4;
    *(float4*)(a + ob) = o;
    if (ah){
        wsplit(ah, al, ob+0, o.x); wsplit(ah, al, ob+1, o.y);
        wsplit(ah, al, ob+2, o.z); wsplit(ah, al, ob+3, o.w);
    }
}
// out = (res?res:0) + x + a1 + 0.5*a2, optional split
__global__ void tfinal_k(const float* __restrict__ x, const float* __restrict__ a1,
                         const float* __restrict__ a2, const float* __restrict__ res,
                         float* __restrict__ out, u16* __restrict__ oh, u16* __restrict__ ol){
    int i = blockIdx.x*256 + threadIdx.x;
    if (i >= BN*KK/4) return;
    float4 xv = ((const float4*)x)[i];
    float4 v1 = ((const float4*)a1)[i];
    float4 v2 = ((const float4*)a2)[i];
    float4 o;
    o.x = xv.x + v1.x + 0.5f*v2.x;
    o.y = xv.y + v1.y + 0.5f*v2.y;
    o.z = xv.z + v1.z + 0.5f*v2.z;
    o.w = xv.w + v1.w + 0.5f*v2.w;
    if (res){ float4 rv = ((const float4*)res)[i]; o.x+=rv.x; o.y+=rv.y; o.z+=rv.z; o.w+=rv.w; }
    ((float4*)out)[i] = o;
    if (oh){
        long ob = (long)i*4;
        wsplit(oh, ol, ob+0, o.x); wsplit(oh, ol, ob+1, o.y);
        wsplit(oh, ol, ob+2, o.z); wsplit(oh, ol, ob+3, o.w);
    }
}
__global__ void copy_k(const float* __restrict__ s, float* __restrict__ d, int n4){
    int i = blockIdx.x*256 + threadIdx.x;
    if (i < n4) ((float4*)d)[i] = ((const float4*)s)[i];
}
__global__ void final_k(const float* __restrict__ a, const float* __restrict__ b,
                        const float* __restrict__ c, float* __restrict__ out){
    int i = blockIdx.x*256 + threadIdx.x;
    if (i >= BN*KK/4) return;
    float4 av = ((const float4*)a)[i], bv = ((const float4*)b)[i], cv = ((const float4*)c)[i];
    float4 o;
    o.x = av.x + bv.x - cv.x; o.y = av.y + bv.y - cv.y;
    o.z = av.z + bv.z - cv.z; o.w = av.w + bv.w - cv.w;
    ((float4*)out)[i] = o;
}
// h_out = h_in + lr*(drive - grad); also split h_out
__global__ void ffn_update_k(const float* __restrict__ hin, float* __restrict__ hout,
                             const float* __restrict__ drive, const float* __restrict__ bmh,
                             const float* __restrict__ mup, const float* __restrict__ lr,
                             u16* __restrict__ hh, u16* __restrict__ hl){
    int i = blockIdx.x*256 + threadIdx.x;
    if (i >= BN*KK/4) return;
    const float lrv = *lr;
    float4 hv = ((const float4*)hin)[i];
    float4 dv = ((const float4*)drive)[i];
    float4 bv = ((const float4*)bmh)[i];
    float4 pv = ((const float4*)mup)[i];
    float4 o;
    o.x = hv.x + lrv*(dv.x - (1e-3f*(hv.x-pv.x) + 1.0f*(hv.x-bv.x)));
    o.y = hv.y + lrv*(dv.y - (1e-3f*(hv.y-pv.y) + 1.0f*(hv.y-bv.y)));
    o.z = hv.z + lrv*(dv.z - (1e-3f*(hv.z-pv.z) + 1.0f*(hv.z-bv.z)));
    o.w = hv.w + lrv*(dv.w - (1e-3f*(hv.w-pv.w) + 1.0f*(hv.w-bv.w)));
    ((float4*)hout)[i] = o;
    long ob = (long)i*4;
    wsplit(hh, hl, ob+0, o.x); wsplit(hh, hl, ob+1, o.y);
    wsplit(hh, hl, ob+2, o.z); wsplit(hh, hl, ob+3, o.w);
}

// ---------------------------------------------------------------- attention prep
__global__ __launch_bounds__(512) void prep2_k(
    const float* __restrict__ qm, const float* __restrict__ km,
    const float* __restrict__ sqm, const float* __restrict__ skm,
    u16* __restrict__ CFh, u16* __restrict__ CFl,
    u16* __restrict__ KSh, u16* __restrict__ KSl, float* __restrict__ dvec)
{
    const int bn = blockIdx.x;
    const int b = bn / NN, n = bn % NN;
    const int h = threadIdx.x >> 6, d = threadIdx.x & 63;
    const long idx = (long)bn*KK + h*DHh + d;
    float q  = qm[idx], k = km[idx];
    float sq = sqm[idx] + 1e-8f;
    float sk = skm[idx] + 1e-8f;
    float inv = 1.f/sq;
    float nqi = -2.f*q*inv;
    float skk = sk + k*k;
    const size_t base = ((size_t)(h*BB + b)*NN + n)*128;
    wsplit(CFh, CFl, base+d,    inv);
    wsplit(CFh, CFl, base+64+d, nqi);
    wsplit(KSh, KSl, base+d,    skk);
    wsplit(KSh, KSl, base+64+d, k);
    float dv = __logf(sk);
    #pragma unroll
    for (int o=32;o>0;o>>=1) dv += __shfl_down(dv,o);
    if (d==0) dvec[((size_t)h*BB + b)*NN + n] = dv;
}

// ---------------------------------------------------------------- V transpose+split: (B,N,512) -> (H*BB, 64, NN)
__global__ __launch_bounds__(256) void vtsplit_k(
    const float* __restrict__ vm, u16* __restrict__ VTh, u16* __restrict__ VTl)
{
    __shared__ float t[64][65];
    const int n0 = blockIdx.x * 64;
    const int h = blockIdx.y, b = blockIdx.z;
    const int tid = threadIdx.x;
    const int c4 = (tid & 15) * 4;
    const int r0 = tid >> 4;
    for (int rr = r0; rr < 64; rr += 16){
        float4 v = *(const float4*)(vm + (size_t)(b*NN + n0 + rr)*KK + h*DHh + c4);
        t[c4+0][rr] = v.x; t[c4+1][rr] = v.y; t[c4+2][rr] = v.z; t[c4+3][rr] = v.w;
    }
    __syncthreads();
    for (int dd = r0; dd < 64; dd += 16){
        size_t base = ((size_t)(h*BB + b)*64 + dd)*NN + n0 + c4;
        #pragma unroll
        for (int q=0;q<4;q++) wsplit(VTh, VTl, base+q, t[dd][c4+q]);
    }
}

// ---------------------------------------------------------------- softmax for a head-group of 4
// block per (b,i): per hg read dot row from S (z=hg*BB+b), softmax(-0.5*dot+0.5*d_j),
// write beta bf16 IN PLACE over S row; accumulate beta_m (g=0: fp32, g=1: +prev, split out).
__global__ __launch_bounds__(256) void softmax2_k(
    float* __restrict__ S, const float* __restrict__ dvec,
    float* __restrict__ betam, u16* __restrict__ BMh, u16* __restrict__ BMl, int g)
{
    __shared__ float s_sc[NN];
    __shared__ float s_bm[NN];
    __shared__ float s_red[4];
    const int tid = threadIdx.x;
    const int b = blockIdx.x / NN, i = blockIdx.x % NN;
    const int L = i + 1;
    for (int j=tid;j<NN;j+=256) s_bm[j]=0.f;
    for (int hg=0; hg<4; ++hg){
        const int z = hg*BB + b;
        float* row = S + ((long)z*NN + i)*NN;
        const float* dp = dvec + ((size_t)(g*4+hg)*BB + b)*NN;
        float lm = -3.0e38f;
        for (int j=tid;j<L;j+=256){
            float sc = -0.5f*row[j] + 0.5f*dp[j];
            s_sc[j] = sc;
            lm = fmaxf(lm, sc);
        }
        #pragma unroll
        for (int o=32;o>0;o>>=1) lm = fmaxf(lm, __shfl_xor(lm, o));
        __syncthreads();
        if ((tid&63)==0) s_red[tid>>6] = lm;
        __syncthreads();
        const float mx = fmaxf(fmaxf(s_red[0],s_red[1]), fmaxf(s_red[2],s_red[3]));
        float ps = 0.f;
        for (int j=tid;j<L;j+=256){
            float e = __expf(s_sc[j]-mx);
            s_sc[j] = e;
            ps += e;
        }
        #pragma unroll
        for (int o=32;o>0;o>>=1) ps += __shfl_xor(ps, o);
        __syncthreads();
        if ((tid&63)==0) s_red[tid>>6] = ps;
        __syncthreads();
        const float isum = 1.f/(s_red[0]+s_red[1]+s_red[2]+s_red[3]);
        u16* brow = (u16*)row;
        for (int j=tid;j<NN;j+=256){
            if (j < L){
                float w = s_sc[j]*isum;
                brow[j] = f2bf(w);
                s_bm[j] += 0.125f*w;
            } else {
                brow[j] = 0;
            }
        }
        __syncthreads();
    }
    const long bmrow = ((long)b*NN + i)*NN;
    if (g == 0){
        for (int j=tid;j<NN;j+=256) betam[bmrow+j] = s_bm[j];
    } else {
        for (int j=tid;j<NN;j+=256){
            float v = betam[bmrow+j] + s_bm[j];
            wsplit(BMh, BMl, bmrow+j, v);
        }
    }
}

// ---------------------------------------------------------------- PV: out[i,d] = sum_j beta[i,j] V[j,d]
// block = (64-row i-tile, z16); 4 waves, wave w owns rows m0+w*16..+16, full N=64, causal K.
__global__ __launch_bounds__(256) void pv_k(
    const u16* __restrict__ Sbeta,  // u16 view of S: row stride 2*NN
    const u16* __restrict__ VTh, const u16* __restrict__ VTl,
    float* __restrict__ x, u16* __restrict__ xh, u16* __restrict__ xl, int g)
{
    __shared__ u16 sA[64*64];    // beta [i][j] 8 KB
    __shared__ u16 sBh[64*64];   // V^T [d][j]
    __shared__ u16 sBl[64*64];
    const int m0 = blockIdx.x*64;
    const int z16 = blockIdx.y;
    const int b = z16 & 3, hg = z16 >> 2;
    const int head = g*4 + hg;
    const int vtz = head*BB + b;
    const int tid = threadIdx.x;
    const int wave = tid>>6, lane = tid&63;
    const int quad = lane>>4, r16 = lane&15;
    f32x4 acc[4];
    #pragma unroll
    for (int j=0;j<4;j++) acc[j]=(f32x4){0.f,0.f,0.f,0.f};
    const int jmax = m0 + 64;
    for (int j0 = 0; j0 < jmax; j0 += 64){
        __syncthreads();
        int c = tid;
        #pragma unroll
        for (int rep=0; rep<2; ++rep, c+=256){
            int row = c >> 3, k8 = (c&7)*8;
            gload16(Sbeta + ((size_t)(z16*NN + m0 + row))*(2*NN) + j0 + k8, &sA[c*8]);
            gload16(VTh + ((size_t)(vtz*64 + row))*NN + j0 + k8, &sBh[c*8]);
            gload16(VTl + ((size_t)(vtz*64 + row))*NN + j0 + k8, &sBl[c*8]);
        }
        __syncthreads();
        #pragma unroll
        for (int kk=0; kk<2; ++kk){
            bf16x8 af = *(const bf16x8*)&sA[(wave*16 + r16)*64 + kk*32 + quad*8];
            #pragma unroll
            for (int nj=0; nj<4; ++nj){
                bf16x8 bh = *(const bf16x8*)&sBh[(nj*16 + r16)*64 + kk*32 + quad*8];
                bf16x8 bl = *(const bf16x8*)&sBl[(nj*16 + r16)*64 + kk*32 + quad*8];
                acc[nj] = __builtin_amdgcn_mfma_f32_16x16x32_bf16(af, bh, acc[nj], 0,0,0);
                acc[nj] = __builtin_amdgcn_mfma_f32_16x16x32_bf16(af, bl, acc[nj], 0,0,0);
            }
        }
    }
    #pragma unroll
    for (int nj=0;nj<4;nj++){
        #pragma unroll
        for (int r=0;r<4;r++){
            int i = m0 + wave*16 + quad*4 + r;
            int d = nj*16 + r16;
            size_t o = ((size_t)(b*NN)+i)*KK + head*64 + d;
            float v = acc[nj][r];
            x[o] = v;
            wsplit(xh, xl, o, v);
        }
    }
}

// ---------------------------------------------------------------- launch
extern "C" void kernel_launch(void* const* d_in, const int* in_sizes, int n_in,
                              void* d_out, int out_size, void* d_ws, size_t ws_size,
                              hipStream_t stream) {
    const float* mu_q    = (const float*)d_in[0];
    const float* sigma_q = (const float*)d_in[1];
    const float* phi     = (const float*)d_in[2];
    const float* gen     = (const float*)d_in[3];
    const float* mu_prior= (const float*)d_in[5];
    const float* Wq = (const float*)d_in[6];
    const float* Wk = (const float*)d_in[7];
    const float* Wv = (const float*)d_in[8];
    const float* Wo = (const float*)d_in[9];
    const float* g1 = (const float*)d_in[10];
    const float* be1= (const float*)d_in[11];
    const float* g2 = (const float*)d_in[12];
    const float* be2= (const float*)d_in[13];
    const float* W1 = (const float*)d_in[14];
    const float* bh1= (const float*)d_in[15];
    const float* W2 = (const float*)d_in[16];
    const float* bh2= (const float*)d_in[17];
    const float* lr = (const float*)d_in[18];
    float* out = (float*)d_out;

    float* w = (float*)d_ws;
    size_t off = 0;
    auto alloc = [&](size_t n){ float* p = w + off; off += (n+3)&~(size_t)3; return p; };
    auto ualloc = [&](size_t n){ return (u16*)alloc((n+1)/2); };

    float* Xb   = alloc((size_t)BN*KK);        // mu_n -> mu_g -> attn_out
    float* A1b  = alloc((size_t)BN*KK);
    float* A2b  = alloc((size_t)BN*KK);
    float* Qb   = alloc((size_t)BN*KK);
    float* Kb   = alloc((size_t)BN*KK);
    float* Vb   = alloc((size_t)BN*KK);
    float* SQb  = alloc((size_t)BN*KK);
    float* SKb  = alloc((size_t)BN*KK);
    float* REG  = alloc((size_t)16*NN*NN);     // Tb / Sbuf / ZH+ZL
    float* Tb   = REG;
    float* Sbuf = REG;
    u16*  ZH    = (u16*)REG;
    u16*  ZL    = ZH + (size_t)BN*HIDd;
    float* Db_  = alloc((size_t)HH*BB*NN);
    float* BMb  = alloc((size_t)BB*NN*NN);
    u16* AH  = ualloc((size_t)BN*HIDd); u16* AL  = ualloc((size_t)BN*HIDd);
    u16* CFh = AH;
    u16* CFl = AH + (size_t)HH*BB*NN*128;
    u16* KSh = AL;
    u16* KSl = AL + (size_t)HH*BB*NN*128;
    u16* VTh = ualloc((size_t)HH*BB*64*NN);
    u16* VTl = ualloc((size_t)HH*BB*64*NN);
    u16* GTh = ualloc((size_t)3*KK*KK); u16* GTl = ualloc((size_t)3*KK*KK);
    u16* WqTh= ualloc((size_t)KK*KK);   u16* WqTl= ualloc((size_t)KK*KK);
    u16* WkTh= ualloc((size_t)KK*KK);   u16* WkTl= ualloc((size_t)KK*KK);
    u16* WvTh= ualloc((size_t)KK*KK);   u16* WvTl= ualloc((size_t)KK*KK);
    u16* WoTh= ualloc((size_t)KK*KK);   u16* WoTl= ualloc((size_t)KK*KK);
    u16* Wq2h= ualloc((size_t)KK*KK);   u16* Wq2l= ualloc((size_t)KK*KK);
    u16* Wk2h= ualloc((size_t)KK*KK);   u16* Wk2l= ualloc((size_t)KK*KK);
    u16* W1Th= ualloc((size_t)KK*HIDd); u16* W1Tl= ualloc((size_t)KK*HIDd);
    u16* W2Th= ualloc((size_t)KK*HIDd); u16* W2Tl= ualloc((size_t)KK*HIDd);
    u16* BMh = ualloc((size_t)BB*NN*NN);u16* BMl = ualloc((size_t)BB*NN*NN);
    u16* HTh = ualloc((size_t)BB*KK*NN);u16* HTl = ualloc((size_t)BB*KK*NN);

    auto gemm = [&](const u16* ah, const u16* al, const u16* bh, const u16* bl,
                    float* C, u16* chi, u16* clo, int M, int Kc, int Nc, int lda,
                    long sA, long sB, long sC, const float* bias, int act,
                    int cskip, int batch){
        dim3 g((Nc+127)/128, M/128, batch);
        gemm_mfma_k<<<g, 256, 0, stream>>>(ah, al, bh, bl, C, chi, clo,
                                           M, Kc, Nc, lda, sA, sB, sC, bias, act, cskip);
    };

    // ---- weight prep (once) ----
    split_k<<<(3*KK*KK+255)/256, 256, 0, stream>>>(gen, GTh, GTl, (long)3*KK*KK);
    {
        dim3 gq(KK/32, KK/32, 1);
        split_t_k<<<gq, 256, 0, stream>>>(Wq, WqTh, WqTl, KK, KK, 0L, 0L, 0);
        split_t_k<<<gq, 256, 0, stream>>>(Wk, WkTh, WkTl, KK, KK, 0L, 0L, 0);
        split_t_k<<<gq, 256, 0, stream>>>(Wv, WvTh, WvTl, KK, KK, 0L, 0L, 0);
        split_t_k<<<gq, 256, 0, stream>>>(Wo, WoTh, WoTl, KK, KK, 0L, 0L, 0);
        split_t_k<<<gq, 256, 0, stream>>>(Wq, Wq2h, Wq2l, KK, KK, 0L, 0L, 1);
        split_t_k<<<gq, 256, 0, stream>>>(Wk, Wk2h, Wk2l, KK, KK, 0L, 0L, 1);
        dim3 g1g(HIDd/32, KK/32, 1);
        split_t_k<<<g1g, 256, 0, stream>>>(W1, W1Th, W1Tl, KK, HIDd, 0L, 0L, 0);
        dim3 g2g(KK/32, HIDd/32, 1);
        split_t_k<<<g2g, 256, 0, stream>>>(W2, W2Th, W2Tl, HIDd, KK, 0L, 0L, 0);
    }

    // ---- phase A: LN1 + forward transport ----
    ln_k<<<BN, 256, 0, stream>>>(mu_q, g1, be1, Xb, AH, AL);
    gemm(AH, AL, GTh, GTl, Tb, 0,0, BN, KK, 3*KK, KK, 0,0,0, nullptr, 0, 0, 1);
    combine_k<<<BN*KK/4/256, 256, 0, stream>>>(Tb, phi, A1b, AH, AL, 1.f);
    gemm(AH, AL, GTh, GTl, Tb, 0,0, BN, KK, 3*KK, KK, 0,0,0, nullptr, 0, 0, 1);
    combine_k<<<BN*KK/4/256, 256, 0, stream>>>(Tb, phi, A2b, 0,0, 1.f);
    tfinal_k<<<BN*KK/4/256, 256, 0, stream>>>(Xb, A1b, A2b, nullptr, Xb, AH, AL);  // mu_g + split

    // ---- phase B: projections + attention prep ----
    gemm(AH, AL, WqTh, WqTl, Qb, 0,0, BN, KK, KK, KK, 0,0,0, nullptr, 0, 0, 1);
    gemm(AH, AL, WkTh, WkTl, Kb, 0,0, BN, KK, KK, KK, 0,0,0, nullptr, 0, 0, 1);
    gemm(AH, AL, WvTh, WvTl, Vb, 0,0, BN, KK, KK, KK, 0,0,0, nullptr, 0, 0, 1);
    split_k<<<(int)(((long)BN*KK+255)/256), 256, 0, stream>>>(sigma_q, AH, AL, (long)BN*KK);
    gemm(AH, AL, Wq2h, Wq2l, SQb, 0,0, BN, KK, KK, KK, 0,0,0, nullptr, 0, 0, 1);
    gemm(AH, AL, Wk2h, Wk2l, SKb, 0,0, BN, KK, KK, KK, 0,0,0, nullptr, 0, 0, 1);
    prep2_k<<<BN, 512, 0, stream>>>(Qb, Kb, SQb, SKb, CFh, CFl, KSh, KSl, Db_);
    {
        dim3 tg(NN/64, HH, BB);
        vtsplit_k<<<tg, 256, 0, stream>>>(Vb, VTh, VTl);
    }

    // ---- phase C: attention, two head-groups of 4 ----
    for (int g = 0; g < 2; ++g){
        size_t cfo = (size_t)g*4*BB*NN*128;
        gemm(CFh+cfo, CFl+cfo, KSh+cfo, KSl+cfo, Sbuf, 0,0,
             NN, 128, NN, 128, (long)NN*128, (long)NN*128, (long)NN*NN,
             nullptr, 0, 1, 16);                                             // causal skip
        softmax2_k<<<BB*NN, 256, 0, stream>>>(Sbuf, Db_, BMb, BMh, BMl, g);
        dim3 pg(NN/64, 16, 1);
        pv_k<<<pg, 256, 0, stream>>>((const u16*)Sbuf, VTh, VTl, Xb, AH, AL, g);
    }

    // ---- phase D: output proj + back transport + residual + LN2 ----
    gemm(AH, AL, WoTh, WoTl, A1b, HTh, HTl, BN, KK, KK, KK, 0,0,0, nullptr, 0, 0, 1); // wo_out fp32+split
    gemm(HTh, HTl, GTh, GTl, Tb, 0,0, BN, KK, 3*KK, KK, 0,0,0, nullptr, 0, 0, 1);
    combine_k<<<BN*KK/4/256, 256, 0, stream>>>(Tb, phi, A2b, AH, AL, -1.f);  // a1' + split
    gemm(AH, AL, GTh, GTl, Tb, 0,0, BN, KK, 3*KK, KK, 0,0,0, nullptr, 0, 0, 1);
    combine_k<<<BN*KK/4/256, 256, 0, stream>>>(Tb, phi, Qb, 0,0, -1.f);      // a2'
    tfinal_k<<<BN*KK/4/256, 256, 0, stream>>>(A1b, A2b, Qb, mu_q, Kb, 0,0);  // mu_res
    ln_k<<<BN, 256, 0, stream>>>(Kb, g2, be2, Vb, AH, AL);                   // mu_n2 + h split

    // ---- phase E: 2 VFE iterations ----
    for (int it=0; it<2; ++it){
        const float* hin = (it==0) ? Vb : SQb;
        gemm(AH, AL, W1Th, W1Tl, 0, ZH, ZL, BN, KK, HIDd, KK, 0,0,0, bh1, 1, 0, 1);
        gemm(ZH, ZL, W2Th, W2Tl, SKb, 0,0, BN, HIDd, KK, HIDd, 0,0,0, bh2, 0, 0, 1);
        {
            dim3 tg(KK/32, NN/32, BB);
            split_t_k<<<tg, 256, 0, stream>>>(hin, HTh, HTl, NN, KK,
                                              (long)NN*KK, (long)KK*NN, 0);
        }
        gemm(BMh, BMl, HTh, HTl, A1b, 0,0, NN, NN, KK, NN,
             (long)NN*NN, (long)KK*NN, (long)NN*KK, nullptr, 0, 2, BB);      // K-causal
        ffn_update_k<<<BN*KK/4/256, 256, 0, stream>>>(hin, SQb, SKb, A1b, mu_prior, lr, AH, AL);
    }

    // ---- phase F: outputs ----
    final_k<<<BN*KK/4/256, 256, 0, stream>>>(Kb, SQb, Vb, out);
    copy_k<<<BN*KK/4/256, 256, 0, stream>>>(sigma_q, out + (size_t)BN*KK, BN*KK/4);
    copy_k<<<(BN*3/4+255)/256, 256, 0, stream>>>(phi, out + 2*(size_t)BN*KK, BN*3/4);

    (void)in_sizes; (void)n_in; (void)out_size; (void)ws_size;
}